// Round 2
// baseline (21487.265 us; speedup 1.0000x reference)
//
#include <hip/hip_runtime.h>
#include <math.h>

// ---------------------------------------------------------------------------
// WanTransformerBlock_VSA — round 2: resubmit of round-1 fp32 baseline
// (previous bench died with UnresponsiveContainer — no data returned).
// All GEMMs: 128x128x16 SIMT SGEMM. Attention: online-softmax, fp32.
// Workspace ~152 MB. Next rounds: bf16 MFMA for the 364 GFLOP of GEMMs.
// ---------------------------------------------------------------------------

namespace {
constexpr int S_   = 4096;
constexpr int D_   = 1536;
constexpr int H_   = 12;
constexpr int DH_  = 128;
constexpr int L_   = 512;
constexpr int NB_  = 64;     // S/64 query/key blocks
constexpr int TOPK = 8;
constexpr int FF_  = 8960;
constexpr float EPS_   = 1e-6f;
constexpr float SCALE_ = 0.08838834764831845f;   // DH^-0.5
constexpr int MCHUNK = 512;                      // FFN row chunk
}

// ---------------------------- reductions -----------------------------------
__device__ __forceinline__ float block_sum_256(float v, float* red) {
#pragma unroll
    for (int off = 32; off > 0; off >>= 1) v += __shfl_down(v, off, 64);
    const int lane = threadIdx.x & 63, w = threadIdx.x >> 6;
    if (lane == 0) red[w] = v;
    __syncthreads();
    v = red[0] + red[1] + red[2] + red[3];
    __syncthreads();
    return v;
}

// ---------------------------- GEMM (fp32) ----------------------------------
// C(M,N) = A(M,K) @ B(K,N) + bias ; act: 0 = none, 1 = tanh-gelu
__global__ __launch_bounds__(256) void gemm_f32(
    const float* __restrict__ A, const float* __restrict__ Bm,
    const float* __restrict__ bias, float* __restrict__ Cm,
    int M, int N, int K, int act)
{
    __shared__ float As[16][128];
    __shared__ float Bs[16][128];
    const int tid = threadIdx.x;
    const int tx = tid & 15, ty = tid >> 4;
    const int n0 = blockIdx.x * 128, m0 = blockIdx.y * 128;

    float acc[8][8];
#pragma unroll
    for (int i = 0; i < 8; i++)
#pragma unroll
        for (int j = 0; j < 8; j++) acc[i][j] = 0.f;

    const int arow  = tid >> 2;   // 0..63
    const int acol4 = tid & 3;    // 0..3

    for (int kt = 0; kt < K; kt += 16) {
#pragma unroll
        for (int i = 0; i < 2; i++) {
            const int r = arow + 64 * i;
            const float4 a = *reinterpret_cast<const float4*>(
                &A[(size_t)(m0 + r) * K + kt + acol4 * 4]);
            As[acol4 * 4 + 0][r] = a.x;
            As[acol4 * 4 + 1][r] = a.y;
            As[acol4 * 4 + 2][r] = a.z;
            As[acol4 * 4 + 3][r] = a.w;
        }
#pragma unroll
        for (int i = 0; i < 2; i++) {
            const int li = tid + 256 * i;
            const int kr = li >> 5, c4 = li & 31;
            const float4 b = *reinterpret_cast<const float4*>(
                &Bm[(size_t)(kt + kr) * N + n0 + c4 * 4]);
            *reinterpret_cast<float4*>(&Bs[kr][c4 * 4]) = b;
        }
        __syncthreads();
#pragma unroll
        for (int kk = 0; kk < 16; kk++) {
            float ar[8], br[8];
#pragma unroll
            for (int i = 0; i < 8; i++) ar[i] = As[kk][ty * 8 + i];
#pragma unroll
            for (int j = 0; j < 8; j++) br[j] = Bs[kk][tx * 8 + j];
#pragma unroll
            for (int i = 0; i < 8; i++)
#pragma unroll
                for (int j = 0; j < 8; j++)
                    acc[i][j] = fmaf(ar[i], br[j], acc[i][j]);
        }
        __syncthreads();
    }

#pragma unroll
    for (int i = 0; i < 8; i++) {
        const int m = m0 + ty * 8 + i;
#pragma unroll
        for (int j = 0; j < 8; j++) {
            const int n = n0 + tx * 8 + j;
            float v = acc[i][j] + (bias ? bias[n] : 0.f);
            if (act == 1) {
                const float x = v;
                const float t = tanhf(0.7978845608028654f * (x + 0.044715f * x * x * x));
                v = 0.5f * x * (1.f + t);
            }
            Cm[(size_t)m * N + n] = v;
        }
    }
}

// ------------------------ LayerNorm / RMSNorm ------------------------------
// out = (x - mean)*rsqrt(var+eps) * (g + ADD1) + b     (one block per token)
template <int ADD1>
__global__ __launch_bounds__(256) void ln_kernel(
    const float* __restrict__ x, float* __restrict__ out,
    const float* __restrict__ g, const float* __restrict__ b)
{
    __shared__ float red[4];
    const size_t s = blockIdx.x;
    const float* xr = x + s * D_;
    float v[6];
    float sm = 0.f;
#pragma unroll
    for (int i = 0; i < 6; i++) { v[i] = xr[threadIdx.x + 256 * i]; sm += v[i]; }
    sm = block_sum_256(sm, red);
    const float mean = sm * (1.f / D_);
    float vs = 0.f;
#pragma unroll
    for (int i = 0; i < 6; i++) { const float d = v[i] - mean; vs += d * d; }
    vs = block_sum_256(vs, red);
    const float rs = rsqrtf(vs * (1.f / D_) + EPS_);
#pragma unroll
    for (int i = 0; i < 6; i++) {
        const int d = threadIdx.x + 256 * i;
        out[s * D_ + d] = (v[i] - mean) * rs * (g[d] + (float)ADD1) + b[d];
    }
}

// in-place RMS norm over D with weight w (one block per row)
__global__ __launch_bounds__(256) void rms_kernel(float* __restrict__ x,
                                                  const float* __restrict__ w)
{
    __shared__ float red[4];
    const size_t s = blockIdx.x;
    float* xr = x + s * D_;
    float v[6];
    float ss = 0.f;
#pragma unroll
    for (int i = 0; i < 6; i++) { v[i] = xr[threadIdx.x + 256 * i]; ss += v[i] * v[i]; }
    ss = block_sum_256(ss, red);
    const float rs = rsqrtf(ss * (1.f / D_) + EPS_);
#pragma unroll
    for (int i = 0; i < 6; i++) {
        const int d = threadIdx.x + 256 * i;
        xr[d] = v[i] * rs * w[d];
    }
}

// ------------------------------- RoPE --------------------------------------
// interleaved pairs within each head, in-place
__global__ void rope_kernel(float* __restrict__ x,
                            const float* __restrict__ cosT,
                            const float* __restrict__ sinT)
{
    const int idx = blockIdx.x * 256 + threadIdx.x;   // S*D/2 pairs
    if (idx >= S_ * (D_ / 2)) return;
    const int s = idx / (D_ / 2), r = idx % (D_ / 2);
    const int h = r >> 6, i = r & 63;
    const size_t base = (size_t)s * D_ + h * 128 + 2 * i;
    const float x1 = x[base], x2 = x[base + 1];
    const float c = cosT[s * 64 + i], sn = sinT[s * 64 + i];
    x[base]     = x1 * c - x2 * sn;
    x[base + 1] = x2 * c + x1 * sn;
}

// --------------------------- elementwise -----------------------------------
__global__ void add_kernel(const float* __restrict__ a, const float* __restrict__ b,
                           float* __restrict__ o, int n)
{
    const int i = blockIdx.x * 256 + threadIdx.x;
    if (i < n) o[i] = a[i] + b[i];
}

// o = h + x * gate[d]   (gate broadcast over tokens)
__global__ void residgate_kernel(const float* __restrict__ h, const float* __restrict__ x,
                                 const float* __restrict__ gate, float* __restrict__ o)
{
    const int i = blockIdx.x * 256 + threadIdx.x;
    if (i < S_ * D_) { const int d = i % D_; o[i] = h[i] + x[i] * gate[d]; }
}

// ------------------------- VSA coarse path ---------------------------------
// block means: qc[h][j][d] = mean_t q[(j*64+t)][h*128+d]
__global__ __launch_bounds__(128) void blockmean_kernel(const float* __restrict__ q,
                                                        float* __restrict__ qc)
{
    const int hb = blockIdx.x;            // H*NB
    const int h = hb >> 6, j = hb & 63;
    const int d = threadIdx.x;
    float sum = 0.f;
    for (int t = 0; t < 64; t++)
        sum += q[(size_t)(j * 64 + t) * D_ + h * 128 + d];
    qc[(size_t)((h << 6) + j) * 128 + d] = sum * (1.f / 64.f);
}

// per (h, i): coarse softmax over 64 key blocks, oc = p@vc, top-8 indices
__global__ __launch_bounds__(64) void coarse_kernel(
    const float* __restrict__ qc, const float* __restrict__ kc,
    const float* __restrict__ vc, float* __restrict__ oc, int* __restrict__ idxout)
{
    const int hb = blockIdx.x;
    const int h = hb >> 6, i = hb & 63;
    const int lane = threadIdx.x;
    __shared__ float p[64];

    const float* qv = qc + (size_t)((h << 6) + i) * 128;
    const float* kv = kc + (size_t)((h << 6) + lane) * 128;
    float sc = 0.f;
    for (int d = 0; d < 128; d++) sc = fmaf(qv[d], kv[d], sc);
    sc *= SCALE_;

    float mx = sc;
#pragma unroll
    for (int off = 32; off > 0; off >>= 1) mx = fmaxf(mx, __shfl_xor(mx, off, 64));
    const float e = expf(sc - mx);
    float sumv = e;
#pragma unroll
    for (int off = 32; off > 0; off >>= 1) sumv += __shfl_xor(sumv, off, 64);
    const float pv = e / sumv;
    p[lane] = pv;
    __syncthreads();

    // oc for dims lane, lane+64
    float o0 = 0.f, o1 = 0.f;
    for (int j = 0; j < 64; j++) {
        const float pj = p[j];
        const float* vr = vc + (size_t)((h << 6) + j) * 128;
        o0 = fmaf(pj, vr[lane], o0);
        o1 = fmaf(pj, vr[lane + 64], o1);
    }
    oc[(size_t)((h << 6) + i) * 128 + lane]      = o0;
    oc[(size_t)((h << 6) + i) * 128 + lane + 64] = o1;

    // iterative wave argmax for top-8 (ties -> lower index, matching top_k)
    float v = pv;
    for (int t = 0; t < TOPK; t++) {
        float bv = v; int bi = lane;
#pragma unroll
        for (int off = 32; off > 0; off >>= 1) {
            const float ov = __shfl_xor(bv, off, 64);
            const int   oi = __shfl_xor(bi, off, 64);
            if (ov > bv || (ov == bv && oi < bi)) { bv = ov; bi = oi; }
        }
        if (lane == 0) idxout[((h << 6) + i) * TOPK + t] = bi;
        if (lane == bi) v = -1.f;   // p >= 0, so -1 acts as -inf
    }
}

// ------------------------- VSA fine path -----------------------------------
// one block per (h, query-block i); thread = (query row r, dim quarter pq)
__global__ __launch_bounds__(256) void fine_attn_kernel(
    const float* __restrict__ q, const float* __restrict__ k,
    const float* __restrict__ v, const float* __restrict__ g,
    const float* __restrict__ oc, const int* __restrict__ idx,
    float* __restrict__ attn)
{
    const int hb = blockIdx.x;
    const int h = hb >> 6, i = hb & 63;
    const int tid = threadIdx.x;
    const int r = tid >> 2, pq = tid & 3;
    const int s = i * 64 + r;
    const size_t qoff = (size_t)s * D_ + h * 128 + pq * 32;

    float qr[32];
#pragma unroll
    for (int j = 0; j < 32; j++) qr[j] = q[qoff + j];

    float m = -1e30f, l = 0.f, acc[32];
#pragma unroll
    for (int j = 0; j < 32; j++) acc[j] = 0.f;

    __shared__ int sel[TOPK];
    if (tid < TOPK) sel[tid] = idx[((h << 6) + i) * TOPK + tid];
    __syncthreads();

    for (int t = 0; t < TOPK; t++) {
        const int jb = sel[t];
        const float* kbase = k + (size_t)jb * 64 * D_ + h * 128 + pq * 32;
        const float* vbase = v + (size_t)jb * 64 * D_ + h * 128 + pq * 32;
        for (int kk = 0; kk < 64; kk++) {
            const float* krow = kbase + (size_t)kk * D_;
            float dot = 0.f;
#pragma unroll
            for (int j = 0; j < 32; j++) dot = fmaf(qr[j], krow[j], dot);
            dot += __shfl_xor(dot, 1, 64);
            dot += __shfl_xor(dot, 2, 64);
            dot *= SCALE_;
            if (dot > m) {
                const float c = expf(m - dot);
                l *= c;
#pragma unroll
                for (int j = 0; j < 32; j++) acc[j] *= c;
                m = dot;
            }
            const float p = expf(dot - m);
            l += p;
            const float* vrow = vbase + (size_t)kk * D_;
#pragma unroll
            for (int j = 0; j < 32; j++) acc[j] = fmaf(p, vrow[j], acc[j]);
        }
    }
    const float inv = 1.f / l;
    const float* ocr = oc + (size_t)((h << 6) + i) * 128 + pq * 32;
#pragma unroll
    for (int j = 0; j < 32; j++)
        attn[qoff + j] = acc[j] * inv + ocr[j] * g[qoff + j];
}

// --------------------------- cross attention -------------------------------
// one block per (h, 64-row query chunk); keys/values: all L rows of head h
__global__ __launch_bounds__(256) void cross_attn_kernel(
    const float* __restrict__ cq, const float* __restrict__ ck,
    const float* __restrict__ cv, float* __restrict__ out)
{
    const int hb = blockIdx.x;
    const int h = hb >> 6, i = hb & 63;
    const int tid = threadIdx.x;
    const int r = tid >> 2, pq = tid & 3;
    const int s = i * 64 + r;
    const size_t qoff = (size_t)s * D_ + h * 128 + pq * 32;

    float qr[32];
#pragma unroll
    for (int j = 0; j < 32; j++) qr[j] = cq[qoff + j];

    float m = -1e30f, l = 0.f, acc[32];
#pragma unroll
    for (int j = 0; j < 32; j++) acc[j] = 0.f;

    for (int kk = 0; kk < L_; kk++) {
        const float* krow = ck + (size_t)kk * D_ + h * 128 + pq * 32;
        float dot = 0.f;
#pragma unroll
        for (int j = 0; j < 32; j++) dot = fmaf(qr[j], krow[j], dot);
        dot += __shfl_xor(dot, 1, 64);
        dot += __shfl_xor(dot, 2, 64);
        dot *= SCALE_;
        if (dot > m) {
            const float c = expf(m - dot);
            l *= c;
#pragma unroll
            for (int j = 0; j < 32; j++) acc[j] *= c;
            m = dot;
        }
        const float p = expf(dot - m);
        l += p;
        const float* vrow = cv + (size_t)kk * D_ + h * 128 + pq * 32;
#pragma unroll
        for (int j = 0; j < 32; j++) acc[j] = fmaf(p, vrow[j], acc[j]);
    }
    const float inv = 1.f / l;
#pragma unroll
    for (int j = 0; j < 32; j++) out[qoff + j] = acc[j] * inv;
}

// ---------------------------------------------------------------------------
extern "C" void kernel_launch(void* const* d_in, const int* in_sizes, int n_in,
                              void* d_out, int out_size, void* d_ws, size_t ws_size,
                              hipStream_t stream)
{
    const float* h_in = (const float*)d_in[0];
    const float* enc  = (const float*)d_in[1];
    const float* temb = (const float*)d_in[2];
    const float* cosT = (const float*)d_in[3];
    const float* sinT = (const float*)d_in[4];
    const float* sst  = (const float*)d_in[5];
    const float* Wq = (const float*)d_in[6];   const float* bq = (const float*)d_in[7];
    const float* Wk = (const float*)d_in[8];   const float* bk = (const float*)d_in[9];
    const float* Wv = (const float*)d_in[10];  const float* bv = (const float*)d_in[11];
    const float* Wg = (const float*)d_in[12];  const float* bg = (const float*)d_in[13];
    const float* Wo = (const float*)d_in[14];  const float* bo = (const float*)d_in[15];
    const float* nq_w  = (const float*)d_in[16];
    const float* nk_w  = (const float*)d_in[17];
    const float* ln1_w = (const float*)d_in[18];
    const float* ln1_b = (const float*)d_in[19];
    const float* cWq = (const float*)d_in[20]; const float* cbq = (const float*)d_in[21];
    const float* cWk = (const float*)d_in[22]; const float* cbk = (const float*)d_in[23];
    const float* cWv = (const float*)d_in[24]; const float* cbv = (const float*)d_in[25];
    const float* cWo = (const float*)d_in[26]; const float* cbo = (const float*)d_in[27];
    const float* cnq_w = (const float*)d_in[28];
    const float* cnk_w = (const float*)d_in[29];
    const float* W1 = (const float*)d_in[30];  const float* b1 = (const float*)d_in[31];
    const float* W2 = (const float*)d_in[32];  const float* b2 = (const float*)d_in[33];
    float* out = (float*)d_out;

    // -------- workspace carve (~152 MB of fp32) --------
    float* ws = (float*)d_ws;
    size_t off = 0;
    auto alloc = [&](size_t n) { float* p = ws + off; off += (n + 63) & ~(size_t)63; return p; };
    float* e_   = alloc(6 * D_);
    float* N_   = alloc((size_t)S_ * D_);   // norm1/attn/norm2/norm3
    float* Q_   = alloc((size_t)S_ * D_);   // q / attn@Wo / cout / resid2
    float* K_   = alloc((size_t)S_ * D_);   // k / resid1
    float* V_   = alloc((size_t)S_ * D_);   // v / cq
    float* G_   = alloc((size_t)S_ * D_);   // g / cctx / ff2
    float* qc_  = alloc((size_t)H_ * NB_ * DH_);
    float* kc_  = alloc((size_t)H_ * NB_ * DH_);
    float* vc_  = alloc((size_t)H_ * NB_ * DH_);
    float* oc_  = alloc((size_t)H_ * NB_ * DH_);
    int*   idx_ = (int*)alloc((size_t)H_ * NB_ * TOPK);
    float* CK_  = alloc((size_t)L_ * D_);
    float* CV_  = alloc((size_t)L_ * D_);
    float* FFC  = alloc((size_t)MCHUNK * FF_);

    const int nSD  = S_ * D_;
    const dim3 b256(256);
    const dim3 gSD((nSD + 255) / 256);

    // e = sst + temb
    add_kernel<<<dim3((6 * D_ + 255) / 256), b256, 0, stream>>>(sst, temb, e_, 6 * D_);

    // norm1 = LN(h)*(1+scale)+shift     (scale=e row1, shift=e row0)
    ln_kernel<1><<<dim3(S_), b256, 0, stream>>>(h_in, N_, e_ + D_, e_);

    // q,k,v,g projections
    {
        const dim3 g(D_ / 128, S_ / 128);
        gemm_f32<<<g, b256, 0, stream>>>(N_, Wq, bq, Q_, S_, D_, D_, 0);
        gemm_f32<<<g, b256, 0, stream>>>(N_, Wk, bk, K_, S_, D_, D_, 0);
        gemm_f32<<<g, b256, 0, stream>>>(N_, Wv, bv, V_, S_, D_, D_, 0);
        gemm_f32<<<g, b256, 0, stream>>>(N_, Wg, bg, G_, S_, D_, D_, 0);
    }
    rms_kernel<<<dim3(S_), b256, 0, stream>>>(Q_, nq_w);
    rms_kernel<<<dim3(S_), b256, 0, stream>>>(K_, nk_w);
    {
        const dim3 g((S_ * (D_ / 2) + 255) / 256);
        rope_kernel<<<g, b256, 0, stream>>>(Q_, cosT, sinT);
        rope_kernel<<<g, b256, 0, stream>>>(K_, cosT, sinT);
    }

    // VSA coarse
    blockmean_kernel<<<dim3(H_ * NB_), dim3(128), 0, stream>>>(Q_, qc_);
    blockmean_kernel<<<dim3(H_ * NB_), dim3(128), 0, stream>>>(K_, kc_);
    blockmean_kernel<<<dim3(H_ * NB_), dim3(128), 0, stream>>>(V_, vc_);
    coarse_kernel<<<dim3(H_ * NB_), dim3(64), 0, stream>>>(qc_, kc_, vc_, oc_, idx_);

    // VSA fine (+ coarse*g combine) -> N_
    fine_attn_kernel<<<dim3(H_ * NB_), b256, 0, stream>>>(Q_, K_, V_, G_, oc_, idx_, N_);

    // attn @ Wo + bo -> Q_ ; resid1 = h + Q_*gate -> K_
    gemm_f32<<<dim3(D_ / 128, S_ / 128), b256, 0, stream>>>(N_, Wo, bo, Q_, S_, D_, D_, 0);
    residgate_kernel<<<gSD, b256, 0, stream>>>(h_in, Q_, e_ + 2 * D_, K_);

    // norm2 = LN(resid1)*ln1_w + ln1_b -> N_
    ln_kernel<0><<<dim3(S_), b256, 0, stream>>>(K_, N_, ln1_w, ln1_b);

    // cross-attn projections
    gemm_f32<<<dim3(D_ / 128, S_ / 128), b256, 0, stream>>>(N_, cWq, cbq, V_, S_, D_, D_, 0);
    rms_kernel<<<dim3(S_), b256, 0, stream>>>(V_, cnq_w);
    gemm_f32<<<dim3(D_ / 128, L_ / 128), b256, 0, stream>>>(enc, cWk, cbk, CK_, L_, D_, D_, 0);
    rms_kernel<<<dim3(L_), b256, 0, stream>>>(CK_, cnk_w);
    gemm_f32<<<dim3(D_ / 128, L_ / 128), b256, 0, stream>>>(enc, cWv, cbv, CV_, L_, D_, D_, 0);

    // cross attention -> G_ ; @cWo -> Q_ ; resid2 = K_ + Q_ -> Q_
    cross_attn_kernel<<<dim3(H_ * NB_), b256, 0, stream>>>(V_, CK_, CV_, G_);
    gemm_f32<<<dim3(D_ / 128, S_ / 128), b256, 0, stream>>>(G_, cWo, cbo, Q_, S_, D_, D_, 0);
    add_kernel<<<gSD, b256, 0, stream>>>(K_, Q_, Q_, nSD);

    // norm3 -> N_ ; FFN chunked: gelu(N_@W1+b1)@W2+b2 -> G_
    ln_kernel<1><<<dim3(S_), b256, 0, stream>>>(Q_, N_, e_ + 4 * D_, e_ + 3 * D_);
    for (int c = 0; c < S_ / MCHUNK; c++) {
        gemm_f32<<<dim3(FF_ / 128, MCHUNK / 128), b256, 0, stream>>>(
            N_ + (size_t)c * MCHUNK * D_, W1, b1, FFC, MCHUNK, FF_, D_, 1);
        gemm_f32<<<dim3(D_ / 128, MCHUNK / 128), b256, 0, stream>>>(
            FFC, W2, b2, G_ + (size_t)c * MCHUNK * D_, MCHUNK, D_, FF_, 0);
    }

    // out = resid2 + ff*c_gate
    residgate_kernel<<<gSD, b256, 0, stream>>>(Q_, G_, e_ + 5 * D_, out);
}

// Round 3
// 1749.064 us; speedup vs baseline: 12.2850x; 12.2850x over previous
//
#include <hip/hip_runtime.h>
#include <math.h>

// ---------------------------------------------------------------------------
// Round 3: bf16 MFMA GEMMs (m97 structure) + MFMA flash attention.
// Top-k decision path (q,k proj -> rms -> rope -> blockmean -> coarse) kept
// fp32-exact via split-bf16 GEMM (hi/lo, 3 passes) for Wq/Wk.
// ---------------------------------------------------------------------------

namespace {
constexpr int S_   = 4096;
constexpr int D_   = 1536;
constexpr int H_   = 12;
constexpr int L_   = 512;
constexpr int TOPK = 8;
constexpr int FF_  = 8960;
constexpr float EPS_   = 1e-6f;
constexpr float SCALE_ = 0.08838834764831845f;   // 128^-0.5
constexpr int MCHUNK = 2048;                     // FFN row chunk
}

typedef __attribute__((ext_vector_type(8))) short short8;
typedef __attribute__((ext_vector_type(4))) float f32x4;

#define AS_GLOBAL __attribute__((address_space(1)))
#define AS_LDS    __attribute__((address_space(3)))

#if defined(__has_builtin)
#  if __has_builtin(__builtin_amdgcn_global_load_lds)
#    define USE_GLL 1
#  endif
#endif
#ifndef USE_GLL
#  define USE_GLL 0
#endif

__device__ __forceinline__ short f2bf(float x) {
    uint32_t u = __float_as_uint(x);
    uint32_t r = (u + 0x7FFFu + ((u >> 16) & 1u)) >> 16;
    return (short)r;
}
__device__ __forceinline__ float bf2f(short s) {
    return __uint_as_float(((uint32_t)(uint16_t)s) << 16);
}
__device__ __forceinline__ float gelu_tanh(float x) {
    const float t = tanhf(0.7978845608028654f * (x + 0.044715f * x * x * x));
    return 0.5f * x * (1.f + t);
}

// ---------------------------- reductions -----------------------------------
__device__ __forceinline__ float block_sum_256(float v, float* red) {
#pragma unroll
    for (int off = 32; off > 0; off >>= 1) v += __shfl_down(v, off, 64);
    const int lane = threadIdx.x & 63, w = threadIdx.x >> 6;
    if (lane == 0) red[w] = v;
    __syncthreads();
    v = red[0] + red[1] + red[2] + red[3];
    __syncthreads();
    return v;
}

// ------------------------- bf16 MFMA GEMM ----------------------------------
// C(M,N) = A(M,K) @ Bt(N,K)^T ; 128x128 tile, BK=32, 4 waves (2x2), each 64x64.
// EPI: 0 = C=acc+bias (f32) ; 1 = C+=acc (f32) ; 2 = Cb=bf16(gelu(acc+bias)) ;
//      3 = Cb=bf16(acc+bias)
template <int EPI>
__global__ __launch_bounds__(256) void gemm_bf16(
    const short* __restrict__ A, const short* __restrict__ Bt,
    const float* __restrict__ bias, float* __restrict__ C,
    short* __restrict__ Cb, int M, int N, int K)
{
    __shared__ __align__(16) short As[128 * 32];
    __shared__ __align__(16) short Bs[128 * 32];
    const int tid = threadIdx.x;
    const int wid = tid >> 6, lane = tid & 63;
    const int wm = wid >> 1, wn = wid & 1;
    const int g16 = lane >> 4, l15 = lane & 15;
    const int m0 = blockIdx.y * 128, n0 = blockIdx.x * 128;

    f32x4 acc[4][4];
#pragma unroll
    for (int i = 0; i < 4; i++)
#pragma unroll
        for (int j = 0; j < 4; j++) acc[i][j] = (f32x4){0.f, 0.f, 0.f, 0.f};

    const int r  = tid >> 2;          // 0..63
    const int c8 = (tid & 3) * 8;     // k element offset

    for (int kt = 0; kt < K; kt += 32) {
#if USE_GLL
        __builtin_amdgcn_global_load_lds(
            (const AS_GLOBAL short*)(A + (size_t)(m0 + r) * K + kt + c8),
            (AS_LDS short*)(As + r * 32 + c8), 16, 0, 0);
        __builtin_amdgcn_global_load_lds(
            (const AS_GLOBAL short*)(A + (size_t)(m0 + r + 64) * K + kt + c8),
            (AS_LDS short*)(As + (r + 64) * 32 + c8), 16, 0, 0);
        __builtin_amdgcn_global_load_lds(
            (const AS_GLOBAL short*)(Bt + (size_t)(n0 + r) * K + kt + c8),
            (AS_LDS short*)(Bs + r * 32 + c8), 16, 0, 0);
        __builtin_amdgcn_global_load_lds(
            (const AS_GLOBAL short*)(Bt + (size_t)(n0 + r + 64) * K + kt + c8),
            (AS_LDS short*)(Bs + (r + 64) * 32 + c8), 16, 0, 0);
#else
        {
            short8 va0 = *(const short8*)(A + (size_t)(m0 + r) * K + kt + c8);
            short8 va1 = *(const short8*)(A + (size_t)(m0 + r + 64) * K + kt + c8);
            short8 vb0 = *(const short8*)(Bt + (size_t)(n0 + r) * K + kt + c8);
            short8 vb1 = *(const short8*)(Bt + (size_t)(n0 + r + 64) * K + kt + c8);
            *(short8*)(As + r * 32 + c8) = va0;
            *(short8*)(As + (r + 64) * 32 + c8) = va1;
            *(short8*)(Bs + r * 32 + c8) = vb0;
            *(short8*)(Bs + (r + 64) * 32 + c8) = vb1;
        }
#endif
        __syncthreads();
        short8 a[4], b[4];
#pragma unroll
        for (int i = 0; i < 4; i++)
            a[i] = *(const short8*)(As + (wm * 64 + i * 16 + l15) * 32 + g16 * 8);
#pragma unroll
        for (int j = 0; j < 4; j++)
            b[j] = *(const short8*)(Bs + (wn * 64 + j * 16 + l15) * 32 + g16 * 8);
#pragma unroll
        for (int i = 0; i < 4; i++)
#pragma unroll
            for (int j = 0; j < 4; j++)
                acc[i][j] = __builtin_amdgcn_mfma_f32_16x16x32_bf16(
                    a[i], b[j], acc[i][j], 0, 0, 0);
        __syncthreads();
    }

#pragma unroll
    for (int i = 0; i < 4; i++) {
#pragma unroll
        for (int j = 0; j < 4; j++) {
            const int col = n0 + wn * 64 + j * 16 + l15;
            const float bv = (EPI == 1) ? 0.f : bias[col];
#pragma unroll
            for (int rr = 0; rr < 4; rr++) {
                const int row = m0 + wm * 64 + i * 16 + g16 * 4 + rr;
                const size_t o = (size_t)row * N + col;
                float v = acc[i][j][rr];
                if (EPI == 0) C[o] = v + bv;
                else if (EPI == 1) C[o] += v;
                else if (EPI == 2) Cb[o] = f2bf(gelu_tanh(v + bv));
                else Cb[o] = f2bf(v + bv);
            }
        }
    }
}

// ---------------------- weight transpose / convert -------------------------
// W (Kd x Nd) f32  ->  Th (Nd x Kd) bf16 [, Tl = bf16(W - Th)]
template <int SPLIT>
__global__ __launch_bounds__(256) void transpose_w(
    const float* __restrict__ W, short* __restrict__ Th, short* __restrict__ Tl,
    int Kd, int Nd)
{
    __shared__ float tile[64][65];
    const int k0 = blockIdx.y * 64, n0 = blockIdx.x * 64;
    for (int f = threadIdx.x; f < 1024; f += 256) {
        const int rr = f >> 4, c4 = (f & 15) * 4;
        const float4 v = *(const float4*)(W + (size_t)(k0 + rr) * Nd + n0 + c4);
        tile[rr][c4 + 0] = v.x; tile[rr][c4 + 1] = v.y;
        tile[rr][c4 + 2] = v.z; tile[rr][c4 + 3] = v.w;
    }
    __syncthreads();
    for (int f = threadIdx.x; f < 1024; f += 256) {
        const int nn = f >> 4, k4 = (f & 15) * 4;
        short4 hv, lv;
        float w0 = tile[k4 + 0][nn], w1 = tile[k4 + 1][nn];
        float w2 = tile[k4 + 2][nn], w3 = tile[k4 + 3][nn];
        hv.x = f2bf(w0); hv.y = f2bf(w1); hv.z = f2bf(w2); hv.w = f2bf(w3);
        *(short4*)(Th + (size_t)(n0 + nn) * Kd + k0 + k4) = hv;
        if (SPLIT) {
            lv.x = f2bf(w0 - bf2f(hv.x)); lv.y = f2bf(w1 - bf2f(hv.y));
            lv.z = f2bf(w2 - bf2f(hv.z)); lv.w = f2bf(w3 - bf2f(hv.w));
            *(short4*)(Tl + (size_t)(n0 + nn) * Kd + k0 + k4) = lv;
        }
    }
}

__global__ void cvt_bf16_kernel(const float* __restrict__ x, short* __restrict__ y, int n4)
{
    const int i = blockIdx.x * 256 + threadIdx.x;
    if (i >= n4) return;
    const float4 v = *(const float4*)(x + (size_t)i * 4);
    short4 o; o.x = f2bf(v.x); o.y = f2bf(v.y); o.z = f2bf(v.z); o.w = f2bf(v.w);
    *(short4*)(y + (size_t)i * 4) = o;
}

// --------------------- LayerNorm (bf16 out, optional split) -----------------
template <int ADD1, int SPLIT>
__global__ __launch_bounds__(256) void ln_bf16(
    const float* __restrict__ x, short* __restrict__ hi, short* __restrict__ lo,
    const float* __restrict__ g, const float* __restrict__ b)
{
    __shared__ float red[4];
    const size_t s = blockIdx.x;
    const float* xr = x + s * D_;
    float v[6];
    float sm = 0.f;
#pragma unroll
    for (int i = 0; i < 6; i++) { v[i] = xr[threadIdx.x + 256 * i]; sm += v[i]; }
    sm = block_sum_256(sm, red);
    const float mean = sm * (1.f / D_);
    float vs = 0.f;
#pragma unroll
    for (int i = 0; i < 6; i++) { const float d = v[i] - mean; vs += d * d; }
    vs = block_sum_256(vs, red);
    const float rs = rsqrtf(vs * (1.f / D_) + EPS_);
#pragma unroll
    for (int i = 0; i < 6; i++) {
        const int d = threadIdx.x + 256 * i;
        const float y = (v[i] - mean) * rs * (g[d] + (float)ADD1) + b[d];
        const short h = f2bf(y);
        hi[s * D_ + d] = h;
        if (SPLIT) lo[s * D_ + d] = f2bf(y - bf2f(h));
    }
}

// in-place RMS norm over D_ (one block per row)
__global__ __launch_bounds__(256) void rms_kernel(float* __restrict__ x,
                                                  const float* __restrict__ w)
{
    __shared__ float red[4];
    const size_t s = blockIdx.x;
    float* xr = x + s * D_;
    float v[6];
    float ss = 0.f;
#pragma unroll
    for (int i = 0; i < 6; i++) { v[i] = xr[threadIdx.x + 256 * i]; ss += v[i] * v[i]; }
    ss = block_sum_256(ss, red);
    const float rs = rsqrtf(ss * (1.f / D_) + EPS_);
#pragma unroll
    for (int i = 0; i < 6; i++) {
        const int d = threadIdx.x + 256 * i;
        xr[d] = v[i] * rs * w[d];
    }
}

// ------------------------------- RoPE --------------------------------------
__global__ void rope_kernel(float* __restrict__ x,
                            const float* __restrict__ cosT,
                            const float* __restrict__ sinT)
{
    const int idx = blockIdx.x * 256 + threadIdx.x;
    if (idx >= S_ * (D_ / 2)) return;
    const int s = idx / (D_ / 2), r = idx % (D_ / 2);
    const int h = r >> 6, i = r & 63;
    const size_t base = (size_t)s * D_ + h * 128 + 2 * i;
    const float x1 = x[base], x2 = x[base + 1];
    const float c = cosT[s * 64 + i], sn = sinT[s * 64 + i];
    x[base]     = x1 * c - x2 * sn;
    x[base + 1] = x2 * c + x1 * sn;
}

// --------------------------- elementwise -----------------------------------
__global__ void add_kernel(const float* __restrict__ a, const float* __restrict__ b,
                           float* __restrict__ o, int n)
{
    const int i = blockIdx.x * 256 + threadIdx.x;
    if (i < n) o[i] = a[i] + b[i];
}

__global__ void residgate_kernel(const float* __restrict__ h, const float* __restrict__ x,
                                 const float* __restrict__ gate, float* __restrict__ o)
{
    const int i = blockIdx.x * 256 + threadIdx.x;
    if (i < S_ * D_) { const int d = i % D_; o[i] = h[i] + x[i] * gate[d]; }
}

// ------------------------- VSA coarse path ---------------------------------
__global__ __launch_bounds__(128) void blockmean_f32(const float* __restrict__ q,
                                                     float* __restrict__ qc)
{
    const int hb = blockIdx.x;
    const int h = hb >> 6, j = hb & 63;
    const int d = threadIdx.x;
    float sum = 0.f;
    for (int t = 0; t < 64; t++)
        sum += q[(size_t)(j * 64 + t) * D_ + h * 128 + d];
    qc[(size_t)hb * 128 + d] = sum * (1.f / 64.f);
}

__global__ __launch_bounds__(128) void blockmean_bf16(const short* __restrict__ q,
                                                      float* __restrict__ qc)
{
    const int hb = blockIdx.x;
    const int h = hb >> 6, j = hb & 63;
    const int d = threadIdx.x;
    float sum = 0.f;
    for (int t = 0; t < 64; t++)
        sum += bf2f(q[(size_t)(j * 64 + t) * D_ + h * 128 + d]);
    qc[(size_t)hb * 128 + d] = sum * (1.f / 64.f);
}

__global__ __launch_bounds__(64) void coarse_kernel(
    const float* __restrict__ qc, const float* __restrict__ kc,
    const float* __restrict__ vc, float* __restrict__ oc, int* __restrict__ idxout)
{
    const int hb = blockIdx.x;
    const int h = hb >> 6, i = hb & 63;
    const int lane = threadIdx.x;
    __shared__ float p[64];

    const float* qv = qc + (size_t)hb * 128;
    const float* kv = kc + (size_t)((h << 6) + lane) * 128;
    float sc = 0.f;
    for (int d = 0; d < 128; d++) sc = fmaf(qv[d], kv[d], sc);
    sc *= SCALE_;

    float mx = sc;
#pragma unroll
    for (int off = 32; off > 0; off >>= 1) mx = fmaxf(mx, __shfl_xor(mx, off, 64));
    const float e = expf(sc - mx);
    float sumv = e;
#pragma unroll
    for (int off = 32; off > 0; off >>= 1) sumv += __shfl_xor(sumv, off, 64);
    const float pv = e / sumv;
    p[lane] = pv;
    __syncthreads();

    float o0 = 0.f, o1 = 0.f;
    for (int j = 0; j < 64; j++) {
        const float pj = p[j];
        const float* vr = vc + (size_t)((h << 6) + j) * 128;
        o0 = fmaf(pj, vr[lane], o0);
        o1 = fmaf(pj, vr[lane + 64], o1);
    }
    oc[(size_t)hb * 128 + lane]      = o0;
    oc[(size_t)hb * 128 + lane + 64] = o1;

    float v = pv;
    for (int t = 0; t < TOPK; t++) {
        float bv = v; int bi = lane;
#pragma unroll
        for (int off = 32; off > 0; off >>= 1) {
            const float ov = __shfl_xor(bv, off, 64);
            const int   oi = __shfl_xor(bi, off, 64);
            if (ov > bv || (ov == bv && oi < bi)) { bv = ov; bi = oi; }
        }
        if (lane == 0) idxout[hb * TOPK + t] = bi;
        if (lane == bi) v = -1.f;
    }
}

// ---------------------- MFMA flash attention -------------------------------
// MODE 0: fine VSA (gathered key blocks, epilogue += oc*g), K fp32, V bf16.
// MODE 1: cross-attn (sequential 8x64 keys), K fp32, V fp32.
// Block = (h, 64-query chunk). 4 waves x 16 q-rows. 64-key tiles.
template <int MODE>
__global__ __launch_bounds__(256) void attn_mfma(
    const float* __restrict__ Qf, const float* __restrict__ Kf,
    const short* __restrict__ Vbb, const float* __restrict__ Vff,
    const short* __restrict__ Gb, const float* __restrict__ ocp,
    const int* __restrict__ idxp, short* __restrict__ Ob)
{
    const int hb = blockIdx.x, h = hb >> 6, ib = hb & 63;
    const int tid = threadIdx.x, wid = tid >> 6, lane = tid & 63;
    const int g16 = lane >> 4, l15 = lane & 15;

    __shared__ __align__(16) short Ks[64 * 128];    // [key][dim], swizzled
    __shared__ __align__(16) short Vst[128 * 64];   // [dim][key], swizzled
    __shared__ __align__(16) short Ps[64 * 80];     // [qrow][key], pad 80
    __shared__ int sel[8];
    if (tid < 8) sel[tid] = (MODE == 0) ? idxp[hb * 8 + tid] : tid;

    // Q fragments (per wave: 16 q-rows), fp32 -> bf16
    short8 qa[4];
    {
        const float* qrow = Qf + (size_t)(ib * 64 + wid * 16 + l15) * D_ + h * 128;
#pragma unroll
        for (int kk = 0; kk < 4; kk++) {
            const float4 f0 = *(const float4*)(qrow + kk * 32 + g16 * 8);
            const float4 f1 = *(const float4*)(qrow + kk * 32 + g16 * 8 + 4);
            short8 v;
            v[0] = f2bf(f0.x); v[1] = f2bf(f0.y); v[2] = f2bf(f0.z); v[3] = f2bf(f0.w);
            v[4] = f2bf(f1.x); v[5] = f2bf(f1.y); v[6] = f2bf(f1.z); v[7] = f2bf(f1.w);
            qa[kk] = v;
        }
    }

    f32x4 o[8];
#pragma unroll
    for (int n2 = 0; n2 < 8; n2++) o[n2] = (f32x4){0.f, 0.f, 0.f, 0.f};
    float mrow[4] = {-3e38f, -3e38f, -3e38f, -3e38f};
    float lrow[4] = {0.f, 0.f, 0.f, 0.f};
    __syncthreads();

    for (int t = 0; t < 8; t++) {
        const int jb = sel[t];
        // --- stage K tile (64x128), row-major, XOR swizzle on 16B units ---
#pragma unroll
        for (int it = 0; it < 4; it++) {
            const int c = tid + 256 * it;
            const int key = c >> 4, d8 = (c & 15) * 8;
            const float* src = Kf + (size_t)(jb * 64 + key) * D_ + h * 128 + d8;
            const float4 f0 = *(const float4*)src;
            const float4 f1 = *(const float4*)(src + 4);
            short8 v;
            v[0] = f2bf(f0.x); v[1] = f2bf(f0.y); v[2] = f2bf(f0.z); v[3] = f2bf(f0.w);
            v[4] = f2bf(f1.x); v[5] = f2bf(f1.y); v[6] = f2bf(f1.z); v[7] = f2bf(f1.w);
            const int byte = (key * 256 + d8 * 2) ^ ((key & 7) << 4);
            *(short8*)((char*)Ks + byte) = v;
        }
        // --- stage V tile transposed ([dim][key]), XOR swizzle ---
#pragma unroll
        for (int it = 0; it < 4; it++) {
            const int c = tid + 256 * it;
            const int key = c & 63, d8 = (c >> 6) * 8;
            float vv[8];
            if (MODE == 0) {
                const short8 v = *(const short8*)(Vbb + (size_t)(jb * 64 + key) * D_ + h * 128 + d8);
#pragma unroll
                for (int j = 0; j < 8; j++) vv[j] = bf2f(v[j]);
            } else {
                const float* src = Vff + (size_t)(jb * 64 + key) * D_ + h * 128 + d8;
                const float4 f0 = *(const float4*)src;
                const float4 f1 = *(const float4*)(src + 4);
                vv[0] = f0.x; vv[1] = f0.y; vv[2] = f0.z; vv[3] = f0.w;
                vv[4] = f1.x; vv[5] = f1.y; vv[6] = f1.z; vv[7] = f1.w;
            }
#pragma unroll
            for (int j = 0; j < 8; j++) {
                const int dim = d8 + j;
                const int byte = (dim * 128 + key * 2) ^ ((dim & 7) << 4);
                *(short*)((char*)Vst + byte) = f2bf(vv[j]);
            }
        }
        __syncthreads();

        // --- S = Q @ K^T (per wave: 16 rows x 64 keys) ---
        f32x4 s[4];
#pragma unroll
        for (int nt = 0; nt < 4; nt++) {
            f32x4 acc = (f32x4){0.f, 0.f, 0.f, 0.f};
            const int key = nt * 16 + l15;
#pragma unroll
            for (int kk = 0; kk < 4; kk++) {
                const int byte = (key * 256 + (kk * 32 + g16 * 8) * 2) ^ ((key & 7) << 4);
                const short8 b = *(const short8*)((char*)Ks + byte);
                acc = __builtin_amdgcn_mfma_f32_16x16x32_bf16(qa[kk], b, acc, 0, 0, 0);
            }
            s[nt] = acc;
        }
#pragma unroll
        for (int nt = 0; nt < 4; nt++)
#pragma unroll
            for (int rr = 0; rr < 4; rr++) s[nt][rr] *= SCALE_;

        // --- online softmax (rows g16*4+rr; 16-lane groups share rows) ---
        float alpha[4];
#pragma unroll
        for (int rr = 0; rr < 4; rr++) {
            float v = fmaxf(fmaxf(s[0][rr], s[1][rr]), fmaxf(s[2][rr], s[3][rr]));
            v = fmaxf(v, __shfl_xor(v, 1, 64));
            v = fmaxf(v, __shfl_xor(v, 2, 64));
            v = fmaxf(v, __shfl_xor(v, 4, 64));
            v = fmaxf(v, __shfl_xor(v, 8, 64));
            const float mn = fmaxf(mrow[rr], v);
            alpha[rr] = expf(mrow[rr] - mn);
            mrow[rr] = mn;
        }
        float rs[4] = {0.f, 0.f, 0.f, 0.f};
#pragma unroll
        for (int nt = 0; nt < 4; nt++)
#pragma unroll
            for (int rr = 0; rr < 4; rr++) {
                const float p = expf(s[nt][rr] - mrow[rr]);
                s[nt][rr] = p;
                rs[rr] += p;
            }
#pragma unroll
        for (int rr = 0; rr < 4; rr++) {
            float v = rs[rr];
            v += __shfl_xor(v, 1, 64);
            v += __shfl_xor(v, 2, 64);
            v += __shfl_xor(v, 4, 64);
            v += __shfl_xor(v, 8, 64);
            lrow[rr] = lrow[rr] * alpha[rr] + v;
        }
#pragma unroll
        for (int n2 = 0; n2 < 8; n2++)
#pragma unroll
            for (int rr = 0; rr < 4; rr++) o[n2][rr] *= alpha[rr];

        // --- P -> LDS (bf16) ---
#pragma unroll
        for (int nt = 0; nt < 4; nt++)
#pragma unroll
            for (int rr = 0; rr < 4; rr++)
                Ps[(wid * 16 + g16 * 4 + rr) * 80 + nt * 16 + l15] = f2bf(s[nt][rr]);

        // --- O += P @ V ---
#pragma unroll
        for (int kk2 = 0; kk2 < 2; kk2++) {
            const short8 pa = *(const short8*)(Ps + (wid * 16 + l15) * 80 + kk2 * 32 + g16 * 8);
#pragma unroll
            for (int n2 = 0; n2 < 8; n2++) {
                const int dim = n2 * 16 + l15;
                const int byte = (dim * 128 + (kk2 * 32 + g16 * 8) * 2) ^ ((dim & 7) << 4);
                const short8 vb = *(const short8*)((char*)Vst + byte);
                o[n2] = __builtin_amdgcn_mfma_f32_16x16x32_bf16(pa, vb, o[n2], 0, 0, 0);
            }
        }
        __syncthreads();
    }

    // --- epilogue ---
#pragma unroll
    for (int n2 = 0; n2 < 8; n2++) {
        const int col = n2 * 16 + l15;
        const float ocv = (MODE == 0) ? ocp[(size_t)hb * 128 + col] : 0.f;
#pragma unroll
        for (int rr = 0; rr < 4; rr++) {
            const int row = ib * 64 + wid * 16 + g16 * 4 + rr;
            float val = o[n2][rr] / lrow[rr];
            if (MODE == 0)
                val += ocv * bf2f(Gb[(size_t)row * D_ + h * 128 + col]);
            Ob[(size_t)row * D_ + h * 128 + col] = f2bf(val);
        }
    }
}

// ---------------------------------------------------------------------------
extern "C" void kernel_launch(void* const* d_in, const int* in_sizes, int n_in,
                              void* d_out, int out_size, void* d_ws, size_t ws_size,
                              hipStream_t stream)
{
    const float* h_in = (const float*)d_in[0];
    const float* enc  = (const float*)d_in[1];
    const float* temb = (const float*)d_in[2];
    const float* cosT = (const float*)d_in[3];
    const float* sinT = (const float*)d_in[4];
    const float* sst  = (const float*)d_in[5];
    const float* Wq = (const float*)d_in[6];   const float* bq = (const float*)d_in[7];
    const float* Wk = (const float*)d_in[8];   const float* bk = (const float*)d_in[9];
    const float* Wv = (const float*)d_in[10];  const float* bv = (const float*)d_in[11];
    const float* Wg = (const float*)d_in[12];  const float* bg = (const float*)d_in[13];
    const float* Wo = (const float*)d_in[14];  const float* bo = (const float*)d_in[15];
    const float* nq_w  = (const float*)d_in[16];
    const float* nk_w  = (const float*)d_in[17];
    const float* ln1_w = (const float*)d_in[18];
    const float* ln1_b = (const float*)d_in[19];
    const float* cWq = (const float*)d_in[20]; const float* cbq = (const float*)d_in[21];
    const float* cWk = (const float*)d_in[22]; const float* cbk = (const float*)d_in[23];
    const float* cWv = (const float*)d_in[24]; const float* cbv = (const float*)d_in[25];
    const float* cWo = (const float*)d_in[26]; const float* cbo = (const float*)d_in[27];
    const float* cnq_w = (const float*)d_in[28];
    const float* cnk_w = (const float*)d_in[29];
    const float* W1 = (const float*)d_in[30];  const float* b1 = (const float*)d_in[31];
    const float* W2 = (const float*)d_in[32];  const float* b2 = (const float*)d_in[33];
    float* out = (float*)d_out;

    // -------- workspace carve (~230 MB) --------
    char* base = (char*)d_ws;
    size_t off = 0;
    auto alloc = [&](size_t bytes) {
        char* p = base + off;
        off += (bytes + 255) & ~(size_t)255;
        return p;
    };
    const size_t SD = (size_t)S_ * D_;
    float* e_   = (float*)alloc(6 * D_ * 4);
    float* Q_   = (float*)alloc(SD * 4);
    float* K_   = (float*)alloc(SD * 4);
    float* CK_  = (float*)alloc((size_t)L_ * D_ * 4);
    float* CV_  = (float*)alloc((size_t)L_ * D_ * 4);
    float* qc_  = (float*)alloc((size_t)H_ * 64 * 128 * 4);
    float* kc_  = (float*)alloc((size_t)H_ * 64 * 128 * 4);
    float* vc_  = (float*)alloc((size_t)H_ * 64 * 128 * 4);
    float* oc_  = (float*)alloc((size_t)H_ * 64 * 128 * 4);
    int*   idx_ = (int*)alloc((size_t)H_ * 64 * TOPK * 4);
    short* Nb   = (short*)alloc(SD * 2);
    short* Nlo  = (short*)alloc(SD * 2);   // FFC alias start (Nlo+Vb+Gb >= MCHUNK*FF)
    short* Vb   = (short*)alloc(SD * 2);
    short* Gb   = (short*)alloc(SD * 2);
    short* attn_b = (short*)alloc(SD * 2);
    short* enc_b  = (short*)alloc((size_t)L_ * D_ * 2);
    const size_t WDD = (size_t)D_ * D_;
    short* Wqh = (short*)alloc(WDD * 2); short* Wql = (short*)alloc(WDD * 2);
    short* Wkh = (short*)alloc(WDD * 2); short* Wkl = (short*)alloc(WDD * 2);
    short* Wvt = (short*)alloc(WDD * 2); short* Wgt = (short*)alloc(WDD * 2);
    short* Wot = (short*)alloc(WDD * 2);
    short* cWqt = (short*)alloc(WDD * 2); short* cWkt = (short*)alloc(WDD * 2);
    short* cWvt = (short*)alloc(WDD * 2); short* cWot = (short*)alloc(WDD * 2);
    short* W1t = (short*)alloc((size_t)D_ * FF_ * 2);
    short* W2t = (short*)alloc((size_t)D_ * FF_ * 2);
    short* FFC = Nlo;   // alias: Nlo/Vb/Gb dead by FFN time

    const dim3 b256(256);
    const int nSD = S_ * D_;
    const dim3 gSD((nSD + 255) / 256);
    const dim3 gDD(D_ / 64, D_ / 64);

    // e = sst + temb
    add_kernel<<<dim3((6 * D_ + 255) / 256), b256, 0, stream>>>(sst, temb, e_, 6 * D_);

    // norm1 -> Nb (hi) + Nlo (lo)
    ln_bf16<1, 1><<<dim3(S_), b256, 0, stream>>>(h_in, Nb, Nlo, e_ + D_, e_);

    // weight transposes
    transpose_w<1><<<gDD, b256, 0, stream>>>(Wq, Wqh, Wql, D_, D_);
    transpose_w<1><<<gDD, b256, 0, stream>>>(Wk, Wkh, Wkl, D_, D_);
    transpose_w<0><<<gDD, b256, 0, stream>>>(Wv, Wvt, nullptr, D_, D_);
    transpose_w<0><<<gDD, b256, 0, stream>>>(Wg, Wgt, nullptr, D_, D_);
    transpose_w<0><<<gDD, b256, 0, stream>>>(Wo, Wot, nullptr, D_, D_);
    transpose_w<0><<<gDD, b256, 0, stream>>>(cWq, cWqt, nullptr, D_, D_);
    transpose_w<0><<<gDD, b256, 0, stream>>>(cWk, cWkt, nullptr, D_, D_);
    transpose_w<0><<<gDD, b256, 0, stream>>>(cWv, cWvt, nullptr, D_, D_);
    transpose_w<0><<<gDD, b256, 0, stream>>>(cWo, cWot, nullptr, D_, D_);
    transpose_w<0><<<dim3(FF_ / 64, D_ / 64), b256, 0, stream>>>(W1, W1t, nullptr, D_, FF_);
    transpose_w<0><<<dim3(D_ / 64, FF_ / 64), b256, 0, stream>>>(W2, W2t, nullptr, FF_, D_);
    cvt_bf16_kernel<<<dim3((L_ * D_ / 4 + 255) / 256), b256, 0, stream>>>(enc, enc_b, L_ * D_ / 4);

    // q,k (split-bf16, 3 passes each), v,g (plain bf16)
    const dim3 gP(D_ / 128, S_ / 128);
    gemm_bf16<0><<<gP, b256, 0, stream>>>(Nb,  Wqh, bq, Q_, nullptr, S_, D_, D_);
    gemm_bf16<1><<<gP, b256, 0, stream>>>(Nb,  Wql, nullptr, Q_, nullptr, S_, D_, D_);
    gemm_bf16<1><<<gP, b256, 0, stream>>>(Nlo, Wqh, nullptr, Q_, nullptr, S_, D_, D_);
    gemm_bf16<0><<<gP, b256, 0, stream>>>(Nb,  Wkh, bk, K_, nullptr, S_, D_, D_);
    gemm_bf16<1><<<gP, b256, 0, stream>>>(Nb,  Wkl, nullptr, K_, nullptr, S_, D_, D_);
    gemm_bf16<1><<<gP, b256, 0, stream>>>(Nlo, Wkh, nullptr, K_, nullptr, S_, D_, D_);
    gemm_bf16<3><<<gP, b256, 0, stream>>>(Nb,  Wvt, bv, nullptr, Vb, S_, D_, D_);
    gemm_bf16<3><<<gP, b256, 0, stream>>>(Nb,  Wgt, bg, nullptr, Gb, S_, D_, D_);

    rms_kernel<<<dim3(S_), b256, 0, stream>>>(Q_, nq_w);
    rms_kernel<<<dim3(S_), b256, 0, stream>>>(K_, nk_w);
    {
        const dim3 g((S_ * (D_ / 2) + 255) / 256);
        rope_kernel<<<g, b256, 0, stream>>>(Q_, cosT, sinT);
        rope_kernel<<<g, b256, 0, stream>>>(K_, cosT, sinT);
    }

    // coarse path (fp32)
    blockmean_f32<<<dim3(H_ * 64), dim3(128), 0, stream>>>(Q_, qc_);
    blockmean_f32<<<dim3(H_ * 64), dim3(128), 0, stream>>>(K_, kc_);
    blockmean_bf16<<<dim3(H_ * 64), dim3(128), 0, stream>>>(Vb, vc_);
    coarse_kernel<<<dim3(H_ * 64), dim3(64), 0, stream>>>(qc_, kc_, vc_, oc_, idx_);

    // fine VSA (MFMA) -> attn_b
    attn_mfma<0><<<dim3(H_ * 64), b256, 0, stream>>>(
        Q_, K_, Vb, nullptr, Gb, oc_, idx_, attn_b);

    // attn @ Wo -> Q_ ; resid1 -> K_
    gemm_bf16<0><<<gP, b256, 0, stream>>>(attn_b, Wot, bo, Q_, nullptr, S_, D_, D_);
    residgate_kernel<<<gSD, b256, 0, stream>>>(h_in, Q_, e_ + 2 * D_, K_);

    // norm2 -> Nb ; cq -> Q_ ; rms
    ln_bf16<0, 0><<<dim3(S_), b256, 0, stream>>>(K_, Nb, nullptr, ln1_w, ln1_b);
    gemm_bf16<0><<<gP, b256, 0, stream>>>(Nb, cWqt, cbq, Q_, nullptr, S_, D_, D_);
    rms_kernel<<<dim3(S_), b256, 0, stream>>>(Q_, cnq_w);

    // ck, cv
    const dim3 gL(D_ / 128, L_ / 128);
    gemm_bf16<0><<<gL, b256, 0, stream>>>(enc_b, cWkt, cbk, CK_, nullptr, L_, D_, D_);
    rms_kernel<<<dim3(L_), b256, 0, stream>>>(CK_, cnk_w);
    gemm_bf16<0><<<gL, b256, 0, stream>>>(enc_b, cWvt, cbv, CV_, nullptr, L_, D_, D_);

    // cross attention (MFMA) -> attn_b ; @cWo -> Q_ ; resid2 -> K_
    attn_mfma<1><<<dim3(H_ * 64), b256, 0, stream>>>(
        Q_, CK_, nullptr, CV_, nullptr, nullptr, nullptr, attn_b);
    gemm_bf16<0><<<gP, b256, 0, stream>>>(attn_b, cWot, cbo, Q_, nullptr, S_, D_, D_);
    add_kernel<<<gSD, b256, 0, stream>>>(K_, Q_, K_, nSD);

    // norm3 -> Nb ; FFN chunks ; ff -> Q_
    ln_bf16<1, 0><<<dim3(S_), b256, 0, stream>>>(K_, Nb, nullptr, e_ + 4 * D_, e_ + 3 * D_);
    for (int c = 0; c < S_ / MCHUNK; c++) {
        gemm_bf16<2><<<dim3(FF_ / 128, MCHUNK / 128), b256, 0, stream>>>(
            Nb + (size_t)c * MCHUNK * D_, W1t, b1, nullptr, FFC, MCHUNK, FF_, D_);
        gemm_bf16<0><<<dim3(D_ / 128, MCHUNK / 128), b256, 0, stream>>>(
            FFC, W2t, b2, Q_ + (size_t)c * MCHUNK * D_, nullptr, MCHUNK, D_, FF_);
    }

    // out = resid2 + ff * c_gate
    residgate_kernel<<<gSD, b256, 0, stream>>>(K_, Q_, e_ + 5 * D_, out);
}

// Round 4
// 1631.945 us; speedup vs baseline: 13.1667x; 1.0718x over previous
//
#include <hip/hip_runtime.h>
#include <math.h>

// ---------------------------------------------------------------------------
// Round 4: GEMM rebuilt — LDS XOR swizzle (conflict-free frag reads, staged
// via pre-swizzled global source) + double-buffered 2-phase pipeline +
// bijective XCD block swizzle. Attention/norm kernels unchanged from round 3.
// ---------------------------------------------------------------------------

namespace {
constexpr int S_   = 4096;
constexpr int D_   = 1536;
constexpr int H_   = 12;
constexpr int L_   = 512;
constexpr int TOPK = 8;
constexpr int FF_  = 8960;
constexpr float EPS_   = 1e-6f;
constexpr float SCALE_ = 0.08838834764831845f;   // 128^-0.5
constexpr int MCHUNK = 2048;                     // FFN row chunk
}

typedef __attribute__((ext_vector_type(8))) short short8;
typedef __attribute__((ext_vector_type(4))) float f32x4;

#define AS_GLOBAL __attribute__((address_space(1)))
#define AS_LDS    __attribute__((address_space(3)))

__device__ __forceinline__ short f2bf(float x) {
    uint32_t u = __float_as_uint(x);
    uint32_t r = (u + 0x7FFFu + ((u >> 16) & 1u)) >> 16;
    return (short)r;
}
__device__ __forceinline__ float bf2f(short s) {
    return __uint_as_float(((uint32_t)(uint16_t)s) << 16);
}
__device__ __forceinline__ float gelu_tanh(float x) {
    const float t = tanhf(0.7978845608028654f * (x + 0.044715f * x * x * x));
    return 0.5f * x * (1.f + t);
}

// ---------------------------- reductions -----------------------------------
__device__ __forceinline__ float block_sum_256(float v, float* red) {
#pragma unroll
    for (int off = 32; off > 0; off >>= 1) v += __shfl_down(v, off, 64);
    const int lane = threadIdx.x & 63, w = threadIdx.x >> 6;
    if (lane == 0) red[w] = v;
    __syncthreads();
    v = red[0] + red[1] + red[2] + red[3];
    __syncthreads();
    return v;
}

// ------------------------- bf16 MFMA GEMM ----------------------------------
// C(M,N) = A(M,K) @ Bt(N,K)^T ; 128x128 tile, BK=32, 4 waves (2x2), 64x64 each.
// LDS tile layout: 512 16B-units; unit for logical (row, u) lives at
// physical unit row*4 + (u ^ ((row>>1)&3))  -> conflict-free frag reads.
// Staged with global_load_lds (linear dest) + pre-swizzled global source.
// Double-buffered: STAGE(next) -> ds_read/MFMA(cur) -> barrier (drains vmcnt).
// EPI: 0 = C=acc+bias (f32) ; 1 = C+=acc (f32) ; 2 = Cb=bf16(gelu(acc+bias)) ;
//      3 = Cb=bf16(acc+bias)
template <int EPI>
__global__ __launch_bounds__(256) void gemm_bf16(
    const short* __restrict__ A, const short* __restrict__ Bt,
    const float* __restrict__ bias, float* __restrict__ C,
    short* __restrict__ Cb, int M, int N, int K)
{
    __shared__ __align__(16) short As[2][128 * 32];
    __shared__ __align__(16) short Bs[2][128 * 32];
    const int tid = threadIdx.x;
    const int wid = tid >> 6, lane = tid & 63;
    const int wm = wid >> 1, wn = wid & 1;
    const int g16 = lane >> 4, l15 = lane & 15;

    // bijective XCD swizzle over the flattened grid (m204)
    const int nwg = gridDim.x * gridDim.y;
    const int bid = blockIdx.y * gridDim.x + blockIdx.x;
    const int qq = nwg >> 3, r8 = nwg & 7;
    const int xcd = bid & 7, lid = bid >> 3;
    const int swz = ((xcd < r8) ? xcd * (qq + 1) : r8 * (qq + 1) + (xcd - r8) * qq) + lid;
    const int m0 = (swz / gridDim.x) * 128, n0 = (swz % gridDim.x) * 128;

    f32x4 acc[4][4];
#pragma unroll
    for (int i = 0; i < 4; i++)
#pragma unroll
        for (int j = 0; j < 4; j++) acc[i][j] = (f32x4){0.f, 0.f, 0.f, 0.f};

    // staging: thread handles units tid and tid+256 of each 512-unit tile
    const int c0 = tid, c1 = tid + 256;
    const int ar0 = c0 >> 2, au0 = (c0 & 3) ^ ((c0 >> 3) & 3);
    const int ar1 = c1 >> 2, au1 = (c1 & 3) ^ ((c1 >> 3) & 3);

    auto STAGE = [&](int buf, int kt) {
        __builtin_amdgcn_global_load_lds(
            (const AS_GLOBAL short*)(A + (size_t)(m0 + ar0) * K + kt + au0 * 8),
            (AS_LDS short*)(As[buf] + c0 * 8), 16, 0, 0);
        __builtin_amdgcn_global_load_lds(
            (const AS_GLOBAL short*)(A + (size_t)(m0 + ar1) * K + kt + au1 * 8),
            (AS_LDS short*)(As[buf] + c1 * 8), 16, 0, 0);
        __builtin_amdgcn_global_load_lds(
            (const AS_GLOBAL short*)(Bt + (size_t)(n0 + ar0) * K + kt + au0 * 8),
            (AS_LDS short*)(Bs[buf] + c0 * 8), 16, 0, 0);
        __builtin_amdgcn_global_load_lds(
            (const AS_GLOBAL short*)(Bt + (size_t)(n0 + ar1) * K + kt + au1 * 8),
            (AS_LDS short*)(Bs[buf] + c1 * 8), 16, 0, 0);
    };

    STAGE(0, 0);
    __syncthreads();                       // vmcnt(0) drain included

    const int nk = K >> 5;
    for (int t = 0; t < nk; ++t) {
        const int cur = t & 1;
        if (t + 1 < nk) STAGE(cur ^ 1, (t + 1) << 5);

        short8 a[4], b[4];
#pragma unroll
        for (int i = 0; i < 4; i++) {
            const int row = wm * 64 + i * 16 + l15;
            a[i] = *(const short8*)(As[cur] + row * 32 + (g16 ^ ((row >> 1) & 3)) * 8);
        }
#pragma unroll
        for (int j = 0; j < 4; j++) {
            const int row = wn * 64 + j * 16 + l15;
            b[j] = *(const short8*)(Bs[cur] + row * 32 + (g16 ^ ((row >> 1) & 3)) * 8);
        }
#pragma unroll
        for (int i = 0; i < 4; i++)
#pragma unroll
            for (int j = 0; j < 4; j++)
                acc[i][j] = __builtin_amdgcn_mfma_f32_16x16x32_bf16(
                    a[i], b[j], acc[i][j], 0, 0, 0);
        __syncthreads();                   // next buf staged; cur reads done
    }

#pragma unroll
    for (int i = 0; i < 4; i++) {
#pragma unroll
        for (int j = 0; j < 4; j++) {
            const int col = n0 + wn * 64 + j * 16 + l15;
            const float bv = (EPI == 1) ? 0.f : bias[col];
#pragma unroll
            for (int rr = 0; rr < 4; rr++) {
                const int row = m0 + wm * 64 + i * 16 + g16 * 4 + rr;
                const size_t o = (size_t)row * N + col;
                float v = acc[i][j][rr];
                if (EPI == 0) C[o] = v + bv;
                else if (EPI == 1) C[o] += v;
                else if (EPI == 2) Cb[o] = f2bf(gelu_tanh(v + bv));
                else Cb[o] = f2bf(v + bv);
            }
        }
    }
}

// ---------------------- weight transpose / convert -------------------------
template <int SPLIT>
__global__ __launch_bounds__(256) void transpose_w(
    const float* __restrict__ W, short* __restrict__ Th, short* __restrict__ Tl,
    int Kd, int Nd)
{
    __shared__ float tile[64][65];
    const int k0 = blockIdx.y * 64, n0 = blockIdx.x * 64;
    for (int f = threadIdx.x; f < 1024; f += 256) {
        const int rr = f >> 4, c4 = (f & 15) * 4;
        const float4 v = *(const float4*)(W + (size_t)(k0 + rr) * Nd + n0 + c4);
        tile[rr][c4 + 0] = v.x; tile[rr][c4 + 1] = v.y;
        tile[rr][c4 + 2] = v.z; tile[rr][c4 + 3] = v.w;
    }
    __syncthreads();
    for (int f = threadIdx.x; f < 1024; f += 256) {
        const int nn = f >> 4, k4 = (f & 15) * 4;
        short4 hv, lv;
        float w0 = tile[k4 + 0][nn], w1 = tile[k4 + 1][nn];
        float w2 = tile[k4 + 2][nn], w3 = tile[k4 + 3][nn];
        hv.x = f2bf(w0); hv.y = f2bf(w1); hv.z = f2bf(w2); hv.w = f2bf(w3);
        *(short4*)(Th + (size_t)(n0 + nn) * Kd + k0 + k4) = hv;
        if (SPLIT) {
            lv.x = f2bf(w0 - bf2f(hv.x)); lv.y = f2bf(w1 - bf2f(hv.y));
            lv.z = f2bf(w2 - bf2f(hv.z)); lv.w = f2bf(w3 - bf2f(hv.w));
            *(short4*)(Tl + (size_t)(n0 + nn) * Kd + k0 + k4) = lv;
        }
    }
}

__global__ void cvt_bf16_kernel(const float* __restrict__ x, short* __restrict__ y, int n4)
{
    const int i = blockIdx.x * 256 + threadIdx.x;
    if (i >= n4) return;
    const float4 v = *(const float4*)(x + (size_t)i * 4);
    short4 o; o.x = f2bf(v.x); o.y = f2bf(v.y); o.z = f2bf(v.z); o.w = f2bf(v.w);
    *(short4*)(y + (size_t)i * 4) = o;
}

// --------------------- LayerNorm (bf16 out, optional split) -----------------
template <int ADD1, int SPLIT>
__global__ __launch_bounds__(256) void ln_bf16(
    const float* __restrict__ x, short* __restrict__ hi, short* __restrict__ lo,
    const float* __restrict__ g, const float* __restrict__ b)
{
    __shared__ float red[4];
    const size_t s = blockIdx.x;
    const float* xr = x + s * D_;
    float v[6];
    float sm = 0.f;
#pragma unroll
    for (int i = 0; i < 6; i++) { v[i] = xr[threadIdx.x + 256 * i]; sm += v[i]; }
    sm = block_sum_256(sm, red);
    const float mean = sm * (1.f / D_);
    float vs = 0.f;
#pragma unroll
    for (int i = 0; i < 6; i++) { const float d = v[i] - mean; vs += d * d; }
    vs = block_sum_256(vs, red);
    const float rs = rsqrtf(vs * (1.f / D_) + EPS_);
#pragma unroll
    for (int i = 0; i < 6; i++) {
        const int d = threadIdx.x + 256 * i;
        const float y = (v[i] - mean) * rs * (g[d] + (float)ADD1) + b[d];
        const short h = f2bf(y);
        hi[s * D_ + d] = h;
        if (SPLIT) lo[s * D_ + d] = f2bf(y - bf2f(h));
    }
}

__global__ __launch_bounds__(256) void rms_kernel(float* __restrict__ x,
                                                  const float* __restrict__ w)
{
    __shared__ float red[4];
    const size_t s = blockIdx.x;
    float* xr = x + s * D_;
    float v[6];
    float ss = 0.f;
#pragma unroll
    for (int i = 0; i < 6; i++) { v[i] = xr[threadIdx.x + 256 * i]; ss += v[i] * v[i]; }
    ss = block_sum_256(ss, red);
    const float rs = rsqrtf(ss * (1.f / D_) + EPS_);
#pragma unroll
    for (int i = 0; i < 6; i++) {
        const int d = threadIdx.x + 256 * i;
        xr[d] = v[i] * rs * w[d];
    }
}

// ------------------------------- RoPE --------------------------------------
__global__ void rope_kernel(float* __restrict__ x,
                            const float* __restrict__ cosT,
                            const float* __restrict__ sinT)
{
    const int idx = blockIdx.x * 256 + threadIdx.x;
    if (idx >= S_ * (D_ / 2)) return;
    const int s = idx / (D_ / 2), r = idx % (D_ / 2);
    const int h = r >> 6, i = r & 63;
    const size_t base = (size_t)s * D_ + h * 128 + 2 * i;
    const float x1 = x[base], x2 = x[base + 1];
    const float c = cosT[s * 64 + i], sn = sinT[s * 64 + i];
    x[base]     = x1 * c - x2 * sn;
    x[base + 1] = x2 * c + x1 * sn;
}

// --------------------------- elementwise -----------------------------------
__global__ void add_kernel(const float* __restrict__ a, const float* __restrict__ b,
                           float* __restrict__ o, int n)
{
    const int i = blockIdx.x * 256 + threadIdx.x;
    if (i < n) o[i] = a[i] + b[i];
}

__global__ void residgate_kernel(const float* __restrict__ h, const float* __restrict__ x,
                                 const float* __restrict__ gate, float* __restrict__ o)
{
    const int i = blockIdx.x * 256 + threadIdx.x;
    if (i < S_ * D_) { const int d = i % D_; o[i] = h[i] + x[i] * gate[d]; }
}

// ------------------------- VSA coarse path ---------------------------------
__global__ __launch_bounds__(128) void blockmean_f32(const float* __restrict__ q,
                                                     float* __restrict__ qc)
{
    const int hb = blockIdx.x;
    const int h = hb >> 6, j = hb & 63;
    const int d = threadIdx.x;
    float sum = 0.f;
    for (int t = 0; t < 64; t++)
        sum += q[(size_t)(j * 64 + t) * D_ + h * 128 + d];
    qc[(size_t)hb * 128 + d] = sum * (1.f / 64.f);
}

__global__ __launch_bounds__(128) void blockmean_bf16(const short* __restrict__ q,
                                                      float* __restrict__ qc)
{
    const int hb = blockIdx.x;
    const int h = hb >> 6, j = hb & 63;
    const int d = threadIdx.x;
    float sum = 0.f;
    for (int t = 0; t < 64; t++)
        sum += bf2f(q[(size_t)(j * 64 + t) * D_ + h * 128 + d]);
    qc[(size_t)hb * 128 + d] = sum * (1.f / 64.f);
}

__global__ __launch_bounds__(64) void coarse_kernel(
    const float* __restrict__ qc, const float* __restrict__ kc,
    const float* __restrict__ vc, float* __restrict__ oc, int* __restrict__ idxout)
{
    const int hb = blockIdx.x;
    const int h = hb >> 6, i = hb & 63;
    const int lane = threadIdx.x;
    __shared__ float p[64];

    const float* qv = qc + (size_t)hb * 128;
    const float* kv = kc + (size_t)((h << 6) + lane) * 128;
    float sc = 0.f;
    for (int d = 0; d < 128; d++) sc = fmaf(qv[d], kv[d], sc);
    sc *= SCALE_;

    float mx = sc;
#pragma unroll
    for (int off = 32; off > 0; off >>= 1) mx = fmaxf(mx, __shfl_xor(mx, off, 64));
    const float e = expf(sc - mx);
    float sumv = e;
#pragma unroll
    for (int off = 32; off > 0; off >>= 1) sumv += __shfl_xor(sumv, off, 64);
    const float pv = e / sumv;
    p[lane] = pv;
    __syncthreads();

    float o0 = 0.f, o1 = 0.f;
    for (int j = 0; j < 64; j++) {
        const float pj = p[j];
        const float* vr = vc + (size_t)((h << 6) + j) * 128;
        o0 = fmaf(pj, vr[lane], o0);
        o1 = fmaf(pj, vr[lane + 64], o1);
    }
    oc[(size_t)hb * 128 + lane]      = o0;
    oc[(size_t)hb * 128 + lane + 64] = o1;

    float v = pv;
    for (int t = 0; t < TOPK; t++) {
        float bv = v; int bi = lane;
#pragma unroll
        for (int off = 32; off > 0; off >>= 1) {
            const float ov = __shfl_xor(bv, off, 64);
            const int   oi = __shfl_xor(bi, off, 64);
            if (ov > bv || (ov == bv && oi < bi)) { bv = ov; bi = oi; }
        }
        if (lane == 0) idxout[hb * TOPK + t] = bi;
        if (lane == bi) v = -1.f;
    }
}

// ---------------------- MFMA flash attention -------------------------------
template <int MODE>
__global__ __launch_bounds__(256) void attn_mfma(
    const float* __restrict__ Qf, const float* __restrict__ Kf,
    const short* __restrict__ Vbb, const float* __restrict__ Vff,
    const short* __restrict__ Gb, const float* __restrict__ ocp,
    const int* __restrict__ idxp, short* __restrict__ Ob)
{
    const int hb = blockIdx.x, h = hb >> 6, ib = hb & 63;
    const int tid = threadIdx.x, wid = tid >> 6, lane = tid & 63;
    const int g16 = lane >> 4, l15 = lane & 15;

    __shared__ __align__(16) short Ks[64 * 128];
    __shared__ __align__(16) short Vst[128 * 64];
    __shared__ __align__(16) short Ps[64 * 80];
    __shared__ int sel[8];
    if (tid < 8) sel[tid] = (MODE == 0) ? idxp[hb * 8 + tid] : tid;

    short8 qa[4];
    {
        const float* qrow = Qf + (size_t)(ib * 64 + wid * 16 + l15) * D_ + h * 128;
#pragma unroll
        for (int kk = 0; kk < 4; kk++) {
            const float4 f0 = *(const float4*)(qrow + kk * 32 + g16 * 8);
            const float4 f1 = *(const float4*)(qrow + kk * 32 + g16 * 8 + 4);
            short8 v;
            v[0] = f2bf(f0.x); v[1] = f2bf(f0.y); v[2] = f2bf(f0.z); v[3] = f2bf(f0.w);
            v[4] = f2bf(f1.x); v[5] = f2bf(f1.y); v[6] = f2bf(f1.z); v[7] = f2bf(f1.w);
            qa[kk] = v;
        }
    }

    f32x4 o[8];
#pragma unroll
    for (int n2 = 0; n2 < 8; n2++) o[n2] = (f32x4){0.f, 0.f, 0.f, 0.f};
    float mrow[4] = {-3e38f, -3e38f, -3e38f, -3e38f};
    float lrow[4] = {0.f, 0.f, 0.f, 0.f};
    __syncthreads();

    for (int t = 0; t < 8; t++) {
        const int jb = sel[t];
#pragma unroll
        for (int it = 0; it < 4; it++) {
            const int c = tid + 256 * it;
            const int key = c >> 4, d8 = (c & 15) * 8;
            const float* src = Kf + (size_t)(jb * 64 + key) * D_ + h * 128 + d8;
            const float4 f0 = *(const float4*)src;
            const float4 f1 = *(const float4*)(src + 4);
            short8 v;
            v[0] = f2bf(f0.x); v[1] = f2bf(f0.y); v[2] = f2bf(f0.z); v[3] = f2bf(f0.w);
            v[4] = f2bf(f1.x); v[5] = f2bf(f1.y); v[6] = f2bf(f1.z); v[7] = f2bf(f1.w);
            const int byte = (key * 256 + d8 * 2) ^ ((key & 7) << 4);
            *(short8*)((char*)Ks + byte) = v;
        }
#pragma unroll
        for (int it = 0; it < 4; it++) {
            const int c = tid + 256 * it;
            const int key = c & 63, d8 = (c >> 6) * 8;
            float vv[8];
            if (MODE == 0) {
                const short8 v = *(const short8*)(Vbb + (size_t)(jb * 64 + key) * D_ + h * 128 + d8);
#pragma unroll
                for (int j = 0; j < 8; j++) vv[j] = bf2f(v[j]);
            } else {
                const float* src = Vff + (size_t)(jb * 64 + key) * D_ + h * 128 + d8;
                const float4 f0 = *(const float4*)src;
                const float4 f1 = *(const float4*)(src + 4);
                vv[0] = f0.x; vv[1] = f0.y; vv[2] = f0.z; vv[3] = f0.w;
                vv[4] = f1.x; vv[5] = f1.y; vv[6] = f1.z; vv[7] = f1.w;
            }
#pragma unroll
            for (int j = 0; j < 8; j++) {
                const int dim = d8 + j;
                const int byte = (dim * 128 + key * 2) ^ ((dim & 7) << 4);
                *(short*)((char*)Vst + byte) = f2bf(vv[j]);
            }
        }
        __syncthreads();

        f32x4 s[4];
#pragma unroll
        for (int nt = 0; nt < 4; nt++) {
            f32x4 acc = (f32x4){0.f, 0.f, 0.f, 0.f};
            const int key = nt * 16 + l15;
#pragma unroll
            for (int kk = 0; kk < 4; kk++) {
                const int byte = (key * 256 + (kk * 32 + g16 * 8) * 2) ^ ((key & 7) << 4);
                const short8 b = *(const short8*)((char*)Ks + byte);
                acc = __builtin_amdgcn_mfma_f32_16x16x32_bf16(qa[kk], b, acc, 0, 0, 0);
            }
            s[nt] = acc;
        }
#pragma unroll
        for (int nt = 0; nt < 4; nt++)
#pragma unroll
            for (int rr = 0; rr < 4; rr++) s[nt][rr] *= SCALE_;

        float alpha[4];
#pragma unroll
        for (int rr = 0; rr < 4; rr++) {
            float v = fmaxf(fmaxf(s[0][rr], s[1][rr]), fmaxf(s[2][rr], s[3][rr]));
            v = fmaxf(v, __shfl_xor(v, 1, 64));
            v = fmaxf(v, __shfl_xor(v, 2, 64));
            v = fmaxf(v, __shfl_xor(v, 4, 64));
            v = fmaxf(v, __shfl_xor(v, 8, 64));
            const float mn = fmaxf(mrow[rr], v);
            alpha[rr] = expf(mrow[rr] - mn);
            mrow[rr] = mn;
        }
        float rs[4] = {0.f, 0.f, 0.f, 0.f};
#pragma unroll
        for (int nt = 0; nt < 4; nt++)
#pragma unroll
            for (int rr = 0; rr < 4; rr++) {
                const float p = expf(s[nt][rr] - mrow[rr]);
                s[nt][rr] = p;
                rs[rr] += p;
            }
#pragma unroll
        for (int rr = 0; rr < 4; rr++) {
            float v = rs[rr];
            v += __shfl_xor(v, 1, 64);
            v += __shfl_xor(v, 2, 64);
            v += __shfl_xor(v, 4, 64);
            v += __shfl_xor(v, 8, 64);
            lrow[rr] = lrow[rr] * alpha[rr] + v;
        }
#pragma unroll
        for (int n2 = 0; n2 < 8; n2++)
#pragma unroll
            for (int rr = 0; rr < 4; rr++) o[n2][rr] *= alpha[rr];

#pragma unroll
        for (int nt = 0; nt < 4; nt++)
#pragma unroll
            for (int rr = 0; rr < 4; rr++)
                Ps[(wid * 16 + g16 * 4 + rr) * 80 + nt * 16 + l15] = f2bf(s[nt][rr]);

#pragma unroll
        for (int kk2 = 0; kk2 < 2; kk2++) {
            const short8 pa = *(const short8*)(Ps + (wid * 16 + l15) * 80 + kk2 * 32 + g16 * 8);
#pragma unroll
            for (int n2 = 0; n2 < 8; n2++) {
                const int dim = n2 * 16 + l15;
                const int byte = (dim * 128 + (kk2 * 32 + g16 * 8) * 2) ^ ((dim & 7) << 4);
                const short8 vb = *(const short8*)((char*)Vst + byte);
                o[n2] = __builtin_amdgcn_mfma_f32_16x16x32_bf16(pa, vb, o[n2], 0, 0, 0);
            }
        }
        __syncthreads();
    }

#pragma unroll
    for (int n2 = 0; n2 < 8; n2++) {
        const int col = n2 * 16 + l15;
        const float ocv = (MODE == 0) ? ocp[(size_t)hb * 128 + col] : 0.f;
#pragma unroll
        for (int rr = 0; rr < 4; rr++) {
            const int row = ib * 64 + wid * 16 + g16 * 4 + rr;
            float val = o[n2][rr] / lrow[rr];
            if (MODE == 0)
                val += ocv * bf2f(Gb[(size_t)row * D_ + h * 128 + col]);
            Ob[(size_t)row * D_ + h * 128 + col] = f2bf(val);
        }
    }
}

// ---------------------------------------------------------------------------
extern "C" void kernel_launch(void* const* d_in, const int* in_sizes, int n_in,
                              void* d_out, int out_size, void* d_ws, size_t ws_size,
                              hipStream_t stream)
{
    const float* h_in = (const float*)d_in[0];
    const float* enc  = (const float*)d_in[1];
    const float* temb = (const float*)d_in[2];
    const float* cosT = (const float*)d_in[3];
    const float* sinT = (const float*)d_in[4];
    const float* sst  = (const float*)d_in[5];
    const float* Wq = (const float*)d_in[6];   const float* bq = (const float*)d_in[7];
    const float* Wk = (const float*)d_in[8];   const float* bk = (const float*)d_in[9];
    const float* Wv = (const float*)d_in[10];  const float* bv = (const float*)d_in[11];
    const float* Wg = (const float*)d_in[12];  const float* bg = (const float*)d_in[13];
    const float* Wo = (const float*)d_in[14];  const float* bo = (const float*)d_in[15];
    const float* nq_w  = (const float*)d_in[16];
    const float* nk_w  = (const float*)d_in[17];
    const float* ln1_w = (const float*)d_in[18];
    const float* ln1_b = (const float*)d_in[19];
    const float* cWq = (const float*)d_in[20]; const float* cbq = (const float*)d_in[21];
    const float* cWk = (const float*)d_in[22]; const float* cbk = (const float*)d_in[23];
    const float* cWv = (const float*)d_in[24]; const float* cbv = (const float*)d_in[25];
    const float* cWo = (const float*)d_in[26]; const float* cbo = (const float*)d_in[27];
    const float* cnq_w = (const float*)d_in[28];
    const float* cnk_w = (const float*)d_in[29];
    const float* W1 = (const float*)d_in[30];  const float* b1 = (const float*)d_in[31];
    const float* W2 = (const float*)d_in[32];  const float* b2 = (const float*)d_in[33];
    float* out = (float*)d_out;

    char* base = (char*)d_ws;
    size_t off = 0;
    auto alloc = [&](size_t bytes) {
        char* p = base + off;
        off += (bytes + 255) & ~(size_t)255;
        return p;
    };
    const size_t SD = (size_t)S_ * D_;
    float* e_   = (float*)alloc(6 * D_ * 4);
    float* Q_   = (float*)alloc(SD * 4);
    float* K_   = (float*)alloc(SD * 4);
    float* CK_  = (float*)alloc((size_t)L_ * D_ * 4);
    float* CV_  = (float*)alloc((size_t)L_ * D_ * 4);
    float* qc_  = (float*)alloc((size_t)H_ * 64 * 128 * 4);
    float* kc_  = (float*)alloc((size_t)H_ * 64 * 128 * 4);
    float* vc_  = (float*)alloc((size_t)H_ * 64 * 128 * 4);
    float* oc_  = (float*)alloc((size_t)H_ * 64 * 128 * 4);
    int*   idx_ = (int*)alloc((size_t)H_ * 64 * TOPK * 4);
    short* Nb   = (short*)alloc(SD * 2);
    short* Nlo  = (short*)alloc(SD * 2);   // FFC alias start
    short* Vb   = (short*)alloc(SD * 2);
    short* Gb   = (short*)alloc(SD * 2);
    short* attn_b = (short*)alloc(SD * 2);
    short* enc_b  = (short*)alloc((size_t)L_ * D_ * 2);
    const size_t WDD = (size_t)D_ * D_;
    short* Wqh = (short*)alloc(WDD * 2); short* Wql = (short*)alloc(WDD * 2);
    short* Wkh = (short*)alloc(WDD * 2); short* Wkl = (short*)alloc(WDD * 2);
    short* Wvt = (short*)alloc(WDD * 2); short* Wgt = (short*)alloc(WDD * 2);
    short* Wot = (short*)alloc(WDD * 2);
    short* cWqt = (short*)alloc(WDD * 2); short* cWkt = (short*)alloc(WDD * 2);
    short* cWvt = (short*)alloc(WDD * 2); short* cWot = (short*)alloc(WDD * 2);
    short* W1t = (short*)alloc((size_t)D_ * FF_ * 2);
    short* W2t = (short*)alloc((size_t)D_ * FF_ * 2);
    short* FFC = Nlo;   // alias: Nlo/Vb/Gb dead by FFN time

    const dim3 b256(256);
    const int nSD = S_ * D_;
    const dim3 gSD((nSD + 255) / 256);
    const dim3 gDD(D_ / 64, D_ / 64);

    add_kernel<<<dim3((6 * D_ + 255) / 256), b256, 0, stream>>>(sst, temb, e_, 6 * D_);
    ln_bf16<1, 1><<<dim3(S_), b256, 0, stream>>>(h_in, Nb, Nlo, e_ + D_, e_);

    transpose_w<1><<<gDD, b256, 0, stream>>>(Wq, Wqh, Wql, D_, D_);
    transpose_w<1><<<gDD, b256, 0, stream>>>(Wk, Wkh, Wkl, D_, D_);
    transpose_w<0><<<gDD, b256, 0, stream>>>(Wv, Wvt, nullptr, D_, D_);
    transpose_w<0><<<gDD, b256, 0, stream>>>(Wg, Wgt, nullptr, D_, D_);
    transpose_w<0><<<gDD, b256, 0, stream>>>(Wo, Wot, nullptr, D_, D_);
    transpose_w<0><<<gDD, b256, 0, stream>>>(cWq, cWqt, nullptr, D_, D_);
    transpose_w<0><<<gDD, b256, 0, stream>>>(cWk, cWkt, nullptr, D_, D_);
    transpose_w<0><<<gDD, b256, 0, stream>>>(cWv, cWvt, nullptr, D_, D_);
    transpose_w<0><<<gDD, b256, 0, stream>>>(cWo, cWot, nullptr, D_, D_);
    transpose_w<0><<<dim3(FF_ / 64, D_ / 64), b256, 0, stream>>>(W1, W1t, nullptr, D_, FF_);
    transpose_w<0><<<dim3(D_ / 64, FF_ / 64), b256, 0, stream>>>(W2, W2t, nullptr, FF_, D_);
    cvt_bf16_kernel<<<dim3((L_ * D_ / 4 + 255) / 256), b256, 0, stream>>>(enc, enc_b, L_ * D_ / 4);

    const dim3 gP(D_ / 128, S_ / 128);
    gemm_bf16<0><<<gP, b256, 0, stream>>>(Nb,  Wqh, bq, Q_, nullptr, S_, D_, D_);
    gemm_bf16<1><<<gP, b256, 0, stream>>>(Nb,  Wql, nullptr, Q_, nullptr, S_, D_, D_);
    gemm_bf16<1><<<gP, b256, 0, stream>>>(Nlo, Wqh, nullptr, Q_, nullptr, S_, D_, D_);
    gemm_bf16<0><<<gP, b256, 0, stream>>>(Nb,  Wkh, bk, K_, nullptr, S_, D_, D_);
    gemm_bf16<1><<<gP, b256, 0, stream>>>(Nb,  Wkl, nullptr, K_, nullptr, S_, D_, D_);
    gemm_bf16<1><<<gP, b256, 0, stream>>>(Nlo, Wkh, nullptr, K_, nullptr, S_, D_, D_);
    gemm_bf16<3><<<gP, b256, 0, stream>>>(Nb,  Wvt, bv, nullptr, Vb, S_, D_, D_);
    gemm_bf16<3><<<gP, b256, 0, stream>>>(Nb,  Wgt, bg, nullptr, Gb, S_, D_, D_);

    rms_kernel<<<dim3(S_), b256, 0, stream>>>(Q_, nq_w);
    rms_kernel<<<dim3(S_), b256, 0, stream>>>(K_, nk_w);
    {
        const dim3 g((S_ * (D_ / 2) + 255) / 256);
        rope_kernel<<<g, b256, 0, stream>>>(Q_, cosT, sinT);
        rope_kernel<<<g, b256, 0, stream>>>(K_, cosT, sinT);
    }

    blockmean_f32<<<dim3(H_ * 64), dim3(128), 0, stream>>>(Q_, qc_);
    blockmean_f32<<<dim3(H_ * 64), dim3(128), 0, stream>>>(K_, kc_);
    blockmean_bf16<<<dim3(H_ * 64), dim3(128), 0, stream>>>(Vb, vc_);
    coarse_kernel<<<dim3(H_ * 64), dim3(64), 0, stream>>>(qc_, kc_, vc_, oc_, idx_);

    attn_mfma<0><<<dim3(H_ * 64), b256, 0, stream>>>(
        Q_, K_, Vb, nullptr, Gb, oc_, idx_, attn_b);

    gemm_bf16<0><<<gP, b256, 0, stream>>>(attn_b, Wot, bo, Q_, nullptr, S_, D_, D_);
    residgate_kernel<<<gSD, b256, 0, stream>>>(h_in, Q_, e_ + 2 * D_, K_);

    ln_bf16<0, 0><<<dim3(S_), b256, 0, stream>>>(K_, Nb, nullptr, ln1_w, ln1_b);
    gemm_bf16<0><<<gP, b256, 0, stream>>>(Nb, cWqt, cbq, Q_, nullptr, S_, D_, D_);
    rms_kernel<<<dim3(S_), b256, 0, stream>>>(Q_, cnq_w);

    const dim3 gL(D_ / 128, L_ / 128);
    gemm_bf16<0><<<gL, b256, 0, stream>>>(enc_b, cWkt, cbk, CK_, nullptr, L_, D_, D_);
    rms_kernel<<<dim3(L_), b256, 0, stream>>>(CK_, cnk_w);
    gemm_bf16<0><<<gL, b256, 0, stream>>>(enc_b, cWvt, cbv, CV_, nullptr, L_, D_, D_);

    attn_mfma<1><<<dim3(H_ * 64), b256, 0, stream>>>(
        Q_, CK_, nullptr, CV_, nullptr, nullptr, nullptr, attn_b);
    gemm_bf16<0><<<gP, b256, 0, stream>>>(attn_b, cWot, cbo, Q_, nullptr, S_, D_, D_);
    add_kernel<<<gSD, b256, 0, stream>>>(K_, Q_, K_, nSD);

    ln_bf16<1, 0><<<dim3(S_), b256, 0, stream>>>(K_, Nb, nullptr, e_ + 4 * D_, e_ + 3 * D_);
    for (int c = 0; c < S_ / MCHUNK; c++) {
        gemm_bf16<2><<<dim3(FF_ / 128, MCHUNK / 128), b256, 0, stream>>>(
            Nb + (size_t)c * MCHUNK * D_, W1t, b1, nullptr, FFC, MCHUNK, FF_, D_);
        gemm_bf16<0><<<dim3(D_ / 128, MCHUNK / 128), b256, 0, stream>>>(
            FFC, W2t, b2, Q_ + (size_t)c * MCHUNK * D_, nullptr, MCHUNK, D_, FF_);
    }

    residgate_kernel<<<gSD, b256, 0, stream>>>(K_, Q_, e_ + 5 * D_, out);
}

// Round 5
// 1487.245 us; speedup vs baseline: 14.4477x; 1.0973x over previous
//
#include <hip/hip_runtime.h>
#include <math.h>

// ---------------------------------------------------------------------------
// Round 5: GEMM K-loop -> counted-vmcnt depth-3 pipeline (T4). Raw s_barrier,
// s_waitcnt vmcnt(8) steady state (never 0 in main loop), 3 LDS buffers.
// Everything else unchanged from round 4 (swizzled LDS, XCD block swizzle).
// ---------------------------------------------------------------------------

namespace {
constexpr int S_   = 4096;
constexpr int D_   = 1536;
constexpr int H_   = 12;
constexpr int L_   = 512;
constexpr int TOPK = 8;
constexpr int FF_  = 8960;
constexpr float EPS_   = 1e-6f;
constexpr float SCALE_ = 0.08838834764831845f;   // 128^-0.5
constexpr int MCHUNK = 2048;                     // FFN row chunk
}

typedef __attribute__((ext_vector_type(8))) short short8;
typedef __attribute__((ext_vector_type(4))) float f32x4;

#define AS_GLOBAL __attribute__((address_space(1)))
#define AS_LDS    __attribute__((address_space(3)))

__device__ __forceinline__ short f2bf(float x) {
    uint32_t u = __float_as_uint(x);
    uint32_t r = (u + 0x7FFFu + ((u >> 16) & 1u)) >> 16;
    return (short)r;
}
__device__ __forceinline__ float bf2f(short s) {
    return __uint_as_float(((uint32_t)(uint16_t)s) << 16);
}
__device__ __forceinline__ float gelu_tanh(float x) {
    const float t = tanhf(0.7978845608028654f * (x + 0.044715f * x * x * x));
    return 0.5f * x * (1.f + t);
}

// ---------------------------- reductions -----------------------------------
__device__ __forceinline__ float block_sum_256(float v, float* red) {
#pragma unroll
    for (int off = 32; off > 0; off >>= 1) v += __shfl_down(v, off, 64);
    const int lane = threadIdx.x & 63, w = threadIdx.x >> 6;
    if (lane == 0) red[w] = v;
    __syncthreads();
    v = red[0] + red[1] + red[2] + red[3];
    __syncthreads();
    return v;
}

// ------------------------- bf16 MFMA GEMM ----------------------------------
// C(M,N) = A(M,K) @ Bt(N,K)^T ; 128x128 tile, BK=32, 4 waves (2x2), 64x64 each.
// Depth-3 software pipeline with counted vmcnt:
//   prologue: STAGE(t=0,1,2)                       (12 loads/wave in flight)
//   iter t  : vmcnt(8) ; s_barrier                 (tile t landed in LDS)
//             ds_read frags ; lgkmcnt(0) ; s_barrier (all waves done reading)
//             STAGE(t+3 -> buf[cur]) ; 16x MFMA
//   tail    : vmcnt(4) then vmcnt(0) peeled.       REQUIRES nk >= 3.
// EPI: 0 = C=acc+bias ; 1 = C+=acc ; 2 = Cb=bf16(gelu(acc+bias)) ; 3 = Cb=bf16(acc+bias)
template <int EPI>
__global__ __launch_bounds__(256) void gemm_bf16(
    const short* __restrict__ A, const short* __restrict__ Bt,
    const float* __restrict__ bias, float* __restrict__ C,
    short* __restrict__ Cb, int M, int N, int K)
{
    __shared__ __align__(16) short As[3][128 * 32];
    __shared__ __align__(16) short Bs[3][128 * 32];
    const int tid = threadIdx.x;
    const int wid = tid >> 6, lane = tid & 63;
    const int wm = wid >> 1, wn = wid & 1;
    const int g16 = lane >> 4, l15 = lane & 15;

    // bijective XCD swizzle over the flattened grid (m204)
    const int nwg = gridDim.x * gridDim.y;
    const int bid = blockIdx.y * gridDim.x + blockIdx.x;
    const int qq = nwg >> 3, r8 = nwg & 7;
    const int xcd = bid & 7, lid = bid >> 3;
    const int swz = ((xcd < r8) ? xcd * (qq + 1) : r8 * (qq + 1) + (xcd - r8) * qq) + lid;
    const int m0 = (swz / gridDim.x) * 128, n0 = (swz % gridDim.x) * 128;

    f32x4 acc[4][4];
#pragma unroll
    for (int i = 0; i < 4; i++)
#pragma unroll
        for (int j = 0; j < 4; j++) acc[i][j] = (f32x4){0.f, 0.f, 0.f, 0.f};

    // staging: thread handles units tid and tid+256 of each 512-unit tile
    const int c0 = tid, c1 = tid + 256;
    const int ar0 = c0 >> 2, au0 = (c0 & 3) ^ ((c0 >> 3) & 3);
    const int ar1 = c1 >> 2, au1 = (c1 & 3) ^ ((c1 >> 3) & 3);

    auto STAGE = [&](int buf, int kt) {
        __builtin_amdgcn_global_load_lds(
            (const AS_GLOBAL short*)(A + (size_t)(m0 + ar0) * K + kt + au0 * 8),
            (AS_LDS short*)(As[buf] + c0 * 8), 16, 0, 0);
        __builtin_amdgcn_global_load_lds(
            (const AS_GLOBAL short*)(A + (size_t)(m0 + ar1) * K + kt + au1 * 8),
            (AS_LDS short*)(As[buf] + c1 * 8), 16, 0, 0);
        __builtin_amdgcn_global_load_lds(
            (const AS_GLOBAL short*)(Bt + (size_t)(n0 + ar0) * K + kt + au0 * 8),
            (AS_LDS short*)(Bs[buf] + c0 * 8), 16, 0, 0);
        __builtin_amdgcn_global_load_lds(
            (const AS_GLOBAL short*)(Bt + (size_t)(n0 + ar1) * K + kt + au1 * 8),
            (AS_LDS short*)(Bs[buf] + c1 * 8), 16, 0, 0);
    };

    const int nk = K >> 5;          // callers guarantee nk >= 3
    STAGE(0, 0);
    STAGE(1, 32);
    STAGE(2, 64);

    int cur = 0;
    for (int t = 0; t < nk; ++t) {
        // counted wait: keep later tiles' loads in flight (T4)
        if (t < nk - 2)       asm volatile("s_waitcnt vmcnt(8)" ::: "memory");
        else if (t == nk - 2) asm volatile("s_waitcnt vmcnt(4)" ::: "memory");
        else                  asm volatile("s_waitcnt vmcnt(0)" ::: "memory");
        __builtin_amdgcn_s_barrier();
        __builtin_amdgcn_sched_barrier(0);

        short8 a[4], b[4];
#pragma unroll
        for (int i = 0; i < 4; i++) {
            const int row = wm * 64 + i * 16 + l15;
            a[i] = *(const short8*)(As[cur] + row * 32 + (g16 ^ ((row >> 1) & 3)) * 8);
        }
#pragma unroll
        for (int j = 0; j < 4; j++) {
            const int row = wn * 64 + j * 16 + l15;
            b[j] = *(const short8*)(Bs[cur] + row * 32 + (g16 ^ ((row >> 1) & 3)) * 8);
        }
        asm volatile("s_waitcnt lgkmcnt(0)" ::: "memory");
        __builtin_amdgcn_sched_barrier(0);
        __builtin_amdgcn_s_barrier();          // all waves done reading buf[cur]
        __builtin_amdgcn_sched_barrier(0);

        if (t + 3 < nk) STAGE(cur, (t + 3) << 5);

#pragma unroll
        for (int i = 0; i < 4; i++)
#pragma unroll
            for (int j = 0; j < 4; j++)
                acc[i][j] = __builtin_amdgcn_mfma_f32_16x16x32_bf16(
                    a[i], b[j], acc[i][j], 0, 0, 0);

        cur = (cur == 2) ? 0 : cur + 1;
    }

#pragma unroll
    for (int i = 0; i < 4; i++) {
#pragma unroll
        for (int j = 0; j < 4; j++) {
            const int col = n0 + wn * 64 + j * 16 + l15;
            const float bv = (EPI == 1) ? 0.f : bias[col];
#pragma unroll
            for (int rr = 0; rr < 4; rr++) {
                const int row = m0 + wm * 64 + i * 16 + g16 * 4 + rr;
                const size_t o = (size_t)row * N + col;
                float v = acc[i][j][rr];
                if (EPI == 0) C[o] = v + bv;
                else if (EPI == 1) C[o] += v;
                else if (EPI == 2) Cb[o] = f2bf(gelu_tanh(v + bv));
                else Cb[o] = f2bf(v + bv);
            }
        }
    }
}

// ---------------------- weight transpose / convert -------------------------
template <int SPLIT>
__global__ __launch_bounds__(256) void transpose_w(
    const float* __restrict__ W, short* __restrict__ Th, short* __restrict__ Tl,
    int Kd, int Nd)
{
    __shared__ float tile[64][65];
    const int k0 = blockIdx.y * 64, n0 = blockIdx.x * 64;
    for (int f = threadIdx.x; f < 1024; f += 256) {
        const int rr = f >> 4, c4 = (f & 15) * 4;
        const float4 v = *(const float4*)(W + (size_t)(k0 + rr) * Nd + n0 + c4);
        tile[rr][c4 + 0] = v.x; tile[rr][c4 + 1] = v.y;
        tile[rr][c4 + 2] = v.z; tile[rr][c4 + 3] = v.w;
    }
    __syncthreads();
    for (int f = threadIdx.x; f < 1024; f += 256) {
        const int nn = f >> 4, k4 = (f & 15) * 4;
        short4 hv, lv;
        float w0 = tile[k4 + 0][nn], w1 = tile[k4 + 1][nn];
        float w2 = tile[k4 + 2][nn], w3 = tile[k4 + 3][nn];
        hv.x = f2bf(w0); hv.y = f2bf(w1); hv.z = f2bf(w2); hv.w = f2bf(w3);
        *(short4*)(Th + (size_t)(n0 + nn) * Kd + k0 + k4) = hv;
        if (SPLIT) {
            lv.x = f2bf(w0 - bf2f(hv.x)); lv.y = f2bf(w1 - bf2f(hv.y));
            lv.z = f2bf(w2 - bf2f(hv.z)); lv.w = f2bf(w3 - bf2f(hv.w));
            *(short4*)(Tl + (size_t)(n0 + nn) * Kd + k0 + k4) = lv;
        }
    }
}

__global__ void cvt_bf16_kernel(const float* __restrict__ x, short* __restrict__ y, int n4)
{
    const int i = blockIdx.x * 256 + threadIdx.x;
    if (i >= n4) return;
    const float4 v = *(const float4*)(x + (size_t)i * 4);
    short4 o; o.x = f2bf(v.x); o.y = f2bf(v.y); o.z = f2bf(v.z); o.w = f2bf(v.w);
    *(short4*)(y + (size_t)i * 4) = o;
}

// --------------------- LayerNorm (bf16 out, optional split) -----------------
template <int ADD1, int SPLIT>
__global__ __launch_bounds__(256) void ln_bf16(
    const float* __restrict__ x, short* __restrict__ hi, short* __restrict__ lo,
    const float* __restrict__ g, const float* __restrict__ b)
{
    __shared__ float red[4];
    const size_t s = blockIdx.x;
    const float* xr = x + s * D_;
    float v[6];
    float sm = 0.f;
#pragma unroll
    for (int i = 0; i < 6; i++) { v[i] = xr[threadIdx.x + 256 * i]; sm += v[i]; }
    sm = block_sum_256(sm, red);
    const float mean = sm * (1.f / D_);
    float vs = 0.f;
#pragma unroll
    for (int i = 0; i < 6; i++) { const float d = v[i] - mean; vs += d * d; }
    vs = block_sum_256(vs, red);
    const float rs = rsqrtf(vs * (1.f / D_) + EPS_);
#pragma unroll
    for (int i = 0; i < 6; i++) {
        const int d = threadIdx.x + 256 * i;
        const float y = (v[i] - mean) * rs * (g[d] + (float)ADD1) + b[d];
        const short h = f2bf(y);
        hi[s * D_ + d] = h;
        if (SPLIT) lo[s * D_ + d] = f2bf(y - bf2f(h));
    }
}

__global__ __launch_bounds__(256) void rms_kernel(float* __restrict__ x,
                                                  const float* __restrict__ w)
{
    __shared__ float red[4];
    const size_t s = blockIdx.x;
    float* xr = x + s * D_;
    float v[6];
    float ss = 0.f;
#pragma unroll
    for (int i = 0; i < 6; i++) { v[i] = xr[threadIdx.x + 256 * i]; ss += v[i] * v[i]; }
    ss = block_sum_256(ss, red);
    const float rs = rsqrtf(ss * (1.f / D_) + EPS_);
#pragma unroll
    for (int i = 0; i < 6; i++) {
        const int d = threadIdx.x + 256 * i;
        xr[d] = v[i] * rs * w[d];
    }
}

// ------------------------------- RoPE --------------------------------------
__global__ void rope_kernel(float* __restrict__ x,
                            const float* __restrict__ cosT,
                            const float* __restrict__ sinT)
{
    const int idx = blockIdx.x * 256 + threadIdx.x;
    if (idx >= S_ * (D_ / 2)) return;
    const int s = idx / (D_ / 2), r = idx % (D_ / 2);
    const int h = r >> 6, i = r & 63;
    const size_t base = (size_t)s * D_ + h * 128 + 2 * i;
    const float x1 = x[base], x2 = x[base + 1];
    const float c = cosT[s * 64 + i], sn = sinT[s * 64 + i];
    x[base]     = x1 * c - x2 * sn;
    x[base + 1] = x2 * c + x1 * sn;
}

// --------------------------- elementwise -----------------------------------
__global__ void add_kernel(const float* __restrict__ a, const float* __restrict__ b,
                           float* __restrict__ o, int n)
{
    const int i = blockIdx.x * 256 + threadIdx.x;
    if (i < n) o[i] = a[i] + b[i];
}

__global__ void residgate_kernel(const float* __restrict__ h, const float* __restrict__ x,
                                 const float* __restrict__ gate, float* __restrict__ o)
{
    const int i = blockIdx.x * 256 + threadIdx.x;
    if (i < S_ * D_) { const int d = i % D_; o[i] = h[i] + x[i] * gate[d]; }
}

// ------------------------- VSA coarse path ---------------------------------
__global__ __launch_bounds__(128) void blockmean_f32(const float* __restrict__ q,
                                                     float* __restrict__ qc)
{
    const int hb = blockIdx.x;
    const int h = hb >> 6, j = hb & 63;
    const int d = threadIdx.x;
    float sum = 0.f;
    for (int t = 0; t < 64; t++)
        sum += q[(size_t)(j * 64 + t) * D_ + h * 128 + d];
    qc[(size_t)hb * 128 + d] = sum * (1.f / 64.f);
}

__global__ __launch_bounds__(128) void blockmean_bf16(const short* __restrict__ q,
                                                      float* __restrict__ qc)
{
    const int hb = blockIdx.x;
    const int h = hb >> 6, j = hb & 63;
    const int d = threadIdx.x;
    float sum = 0.f;
    for (int t = 0; t < 64; t++)
        sum += bf2f(q[(size_t)(j * 64 + t) * D_ + h * 128 + d]);
    qc[(size_t)hb * 128 + d] = sum * (1.f / 64.f);
}

__global__ __launch_bounds__(64) void coarse_kernel(
    const float* __restrict__ qc, const float* __restrict__ kc,
    const float* __restrict__ vc, float* __restrict__ oc, int* __restrict__ idxout)
{
    const int hb = blockIdx.x;
    const int h = hb >> 6, i = hb & 63;
    const int lane = threadIdx.x;
    __shared__ float p[64];

    const float* qv = qc + (size_t)hb * 128;
    const float* kv = kc + (size_t)((h << 6) + lane) * 128;
    float sc = 0.f;
    for (int d = 0; d < 128; d++) sc = fmaf(qv[d], kv[d], sc);
    sc *= SCALE_;

    float mx = sc;
#pragma unroll
    for (int off = 32; off > 0; off >>= 1) mx = fmaxf(mx, __shfl_xor(mx, off, 64));
    const float e = expf(sc - mx);
    float sumv = e;
#pragma unroll
    for (int off = 32; off > 0; off >>= 1) sumv += __shfl_xor(sumv, off, 64);
    const float pv = e / sumv;
    p[lane] = pv;
    __syncthreads();

    float o0 = 0.f, o1 = 0.f;
    for (int j = 0; j < 64; j++) {
        const float pj = p[j];
        const float* vr = vc + (size_t)((h << 6) + j) * 128;
        o0 = fmaf(pj, vr[lane], o0);
        o1 = fmaf(pj, vr[lane + 64], o1);
    }
    oc[(size_t)hb * 128 + lane]      = o0;
    oc[(size_t)hb * 128 + lane + 64] = o1;

    float v = pv;
    for (int t = 0; t < TOPK; t++) {
        float bv = v; int bi = lane;
#pragma unroll
        for (int off = 32; off > 0; off >>= 1) {
            const float ov = __shfl_xor(bv, off, 64);
            const int   oi = __shfl_xor(bi, off, 64);
            if (ov > bv || (ov == bv && oi < bi)) { bv = ov; bi = oi; }
        }
        if (lane == 0) idxout[hb * TOPK + t] = bi;
        if (lane == bi) v = -1.f;
    }
}

// ---------------------- MFMA flash attention -------------------------------
template <int MODE>
__global__ __launch_bounds__(256) void attn_mfma(
    const float* __restrict__ Qf, const float* __restrict__ Kf,
    const short* __restrict__ Vbb, const float* __restrict__ Vff,
    const short* __restrict__ Gb, const float* __restrict__ ocp,
    const int* __restrict__ idxp, short* __restrict__ Ob)
{
    const int hb = blockIdx.x, h = hb >> 6, ib = hb & 63;
    const int tid = threadIdx.x, wid = tid >> 6, lane = tid & 63;
    const int g16 = lane >> 4, l15 = lane & 15;

    __shared__ __align__(16) short Ks[64 * 128];
    __shared__ __align__(16) short Vst[128 * 64];
    __shared__ __align__(16) short Ps[64 * 80];
    __shared__ int sel[8];
    if (tid < 8) sel[tid] = (MODE == 0) ? idxp[hb * 8 + tid] : tid;

    short8 qa[4];
    {
        const float* qrow = Qf + (size_t)(ib * 64 + wid * 16 + l15) * D_ + h * 128;
#pragma unroll
        for (int kk = 0; kk < 4; kk++) {
            const float4 f0 = *(const float4*)(qrow + kk * 32 + g16 * 8);
            const float4 f1 = *(const float4*)(qrow + kk * 32 + g16 * 8 + 4);
            short8 v;
            v[0] = f2bf(f0.x); v[1] = f2bf(f0.y); v[2] = f2bf(f0.z); v[3] = f2bf(f0.w);
            v[4] = f2bf(f1.x); v[5] = f2bf(f1.y); v[6] = f2bf(f1.z); v[7] = f2bf(f1.w);
            qa[kk] = v;
        }
    }

    f32x4 o[8];
#pragma unroll
    for (int n2 = 0; n2 < 8; n2++) o[n2] = (f32x4){0.f, 0.f, 0.f, 0.f};
    float mrow[4] = {-3e38f, -3e38f, -3e38f, -3e38f};
    float lrow[4] = {0.f, 0.f, 0.f, 0.f};
    __syncthreads();

    for (int t = 0; t < 8; t++) {
        const int jb = sel[t];
#pragma unroll
        for (int it = 0; it < 4; it++) {
            const int c = tid + 256 * it;
            const int key = c >> 4, d8 = (c & 15) * 8;
            const float* src = Kf + (size_t)(jb * 64 + key) * D_ + h * 128 + d8;
            const float4 f0 = *(const float4*)src;
            const float4 f1 = *(const float4*)(src + 4);
            short8 v;
            v[0] = f2bf(f0.x); v[1] = f2bf(f0.y); v[2] = f2bf(f0.z); v[3] = f2bf(f0.w);
            v[4] = f2bf(f1.x); v[5] = f2bf(f1.y); v[6] = f2bf(f1.z); v[7] = f2bf(f1.w);
            const int byte = (key * 256 + d8 * 2) ^ ((key & 7) << 4);
            *(short8*)((char*)Ks + byte) = v;
        }
#pragma unroll
        for (int it = 0; it < 4; it++) {
            const int c = tid + 256 * it;
            const int key = c & 63, d8 = (c >> 6) * 8;
            float vv[8];
            if (MODE == 0) {
                const short8 v = *(const short8*)(Vbb + (size_t)(jb * 64 + key) * D_ + h * 128 + d8);
#pragma unroll
                for (int j = 0; j < 8; j++) vv[j] = bf2f(v[j]);
            } else {
                const float* src = Vff + (size_t)(jb * 64 + key) * D_ + h * 128 + d8;
                const float4 f0 = *(const float4*)src;
                const float4 f1 = *(const float4*)(src + 4);
                vv[0] = f0.x; vv[1] = f0.y; vv[2] = f0.z; vv[3] = f0.w;
                vv[4] = f1.x; vv[5] = f1.y; vv[6] = f1.z; vv[7] = f1.w;
            }
#pragma unroll
            for (int j = 0; j < 8; j++) {
                const int dim = d8 + j;
                const int byte = (dim * 128 + key * 2) ^ ((dim & 7) << 4);
                *(short*)((char*)Vst + byte) = f2bf(vv[j]);
            }
        }
        __syncthreads();

        f32x4 s[4];
#pragma unroll
        for (int nt = 0; nt < 4; nt++) {
            f32x4 acc = (f32x4){0.f, 0.f, 0.f, 0.f};
            const int key = nt * 16 + l15;
#pragma unroll
            for (int kk = 0; kk < 4; kk++) {
                const int byte = (key * 256 + (kk * 32 + g16 * 8) * 2) ^ ((key & 7) << 4);
                const short8 b = *(const short8*)((char*)Ks + byte);
                acc = __builtin_amdgcn_mfma_f32_16x16x32_bf16(qa[kk], b, acc, 0, 0, 0);
            }
            s[nt] = acc;
        }
#pragma unroll
        for (int nt = 0; nt < 4; nt++)
#pragma unroll
            for (int rr = 0; rr < 4; rr++) s[nt][rr] *= SCALE_;

        float alpha[4];
#pragma unroll
        for (int rr = 0; rr < 4; rr++) {
            float v = fmaxf(fmaxf(s[0][rr], s[1][rr]), fmaxf(s[2][rr], s[3][rr]));
            v = fmaxf(v, __shfl_xor(v, 1, 64));
            v = fmaxf(v, __shfl_xor(v, 2, 64));
            v = fmaxf(v, __shfl_xor(v, 4, 64));
            v = fmaxf(v, __shfl_xor(v, 8, 64));
            const float mn = fmaxf(mrow[rr], v);
            alpha[rr] = expf(mrow[rr] - mn);
            mrow[rr] = mn;
        }
        float rs[4] = {0.f, 0.f, 0.f, 0.f};
#pragma unroll
        for (int nt = 0; nt < 4; nt++)
#pragma unroll
            for (int rr = 0; rr < 4; rr++) {
                const float p = expf(s[nt][rr] - mrow[rr]);
                s[nt][rr] = p;
                rs[rr] += p;
            }
#pragma unroll
        for (int rr = 0; rr < 4; rr++) {
            float v = rs[rr];
            v += __shfl_xor(v, 1, 64);
            v += __shfl_xor(v, 2, 64);
            v += __shfl_xor(v, 4, 64);
            v += __shfl_xor(v, 8, 64);
            lrow[rr] = lrow[rr] * alpha[rr] + v;
        }
#pragma unroll
        for (int n2 = 0; n2 < 8; n2++)
#pragma unroll
            for (int rr = 0; rr < 4; rr++) o[n2][rr] *= alpha[rr];

#pragma unroll
        for (int nt = 0; nt < 4; nt++)
#pragma unroll
            for (int rr = 0; rr < 4; rr++)
                Ps[(wid * 16 + g16 * 4 + rr) * 80 + nt * 16 + l15] = f2bf(s[nt][rr]);

#pragma unroll
        for (int kk2 = 0; kk2 < 2; kk2++) {
            const short8 pa = *(const short8*)(Ps + (wid * 16 + l15) * 80 + kk2 * 32 + g16 * 8);
#pragma unroll
            for (int n2 = 0; n2 < 8; n2++) {
                const int dim = n2 * 16 + l15;
                const int byte = (dim * 128 + (kk2 * 32 + g16 * 8) * 2) ^ ((dim & 7) << 4);
                const short8 vb = *(const short8*)((char*)Vst + byte);
                o[n2] = __builtin_amdgcn_mfma_f32_16x16x32_bf16(pa, vb, o[n2], 0, 0, 0);
            }
        }
        __syncthreads();
    }

#pragma unroll
    for (int n2 = 0; n2 < 8; n2++) {
        const int col = n2 * 16 + l15;
        const float ocv = (MODE == 0) ? ocp[(size_t)hb * 128 + col] : 0.f;
#pragma unroll
        for (int rr = 0; rr < 4; rr++) {
            const int row = ib * 64 + wid * 16 + g16 * 4 + rr;
            float val = o[n2][rr] / lrow[rr];
            if (MODE == 0)
                val += ocv * bf2f(Gb[(size_t)row * D_ + h * 128 + col]);
            Ob[(size_t)row * D_ + h * 128 + col] = f2bf(val);
        }
    }
}

// ---------------------------------------------------------------------------
extern "C" void kernel_launch(void* const* d_in, const int* in_sizes, int n_in,
                              void* d_out, int out_size, void* d_ws, size_t ws_size,
                              hipStream_t stream)
{
    const float* h_in = (const float*)d_in[0];
    const float* enc  = (const float*)d_in[1];
    const float* temb = (const float*)d_in[2];
    const float* cosT = (const float*)d_in[3];
    const float* sinT = (const float*)d_in[4];
    const float* sst  = (const float*)d_in[5];
    const float* Wq = (const float*)d_in[6];   const float* bq = (const float*)d_in[7];
    const float* Wk = (const float*)d_in[8];   const float* bk = (const float*)d_in[9];
    const float* Wv = (const float*)d_in[10];  const float* bv = (const float*)d_in[11];
    const float* Wg = (const float*)d_in[12];  const float* bg = (const float*)d_in[13];
    const float* Wo = (const float*)d_in[14];  const float* bo = (const float*)d_in[15];
    const float* nq_w  = (const float*)d_in[16];
    const float* nk_w  = (const float*)d_in[17];
    const float* ln1_w = (const float*)d_in[18];
    const float* ln1_b = (const float*)d_in[19];
    const float* cWq = (const float*)d_in[20]; const float* cbq = (const float*)d_in[21];
    const float* cWk = (const float*)d_in[22]; const float* cbk = (const float*)d_in[23];
    const float* cWv = (const float*)d_in[24]; const float* cbv = (const float*)d_in[25];
    const float* cWo = (const float*)d_in[26]; const float* cbo = (const float*)d_in[27];
    const float* cnq_w = (const float*)d_in[28];
    const float* cnk_w = (const float*)d_in[29];
    const float* W1 = (const float*)d_in[30];  const float* b1 = (const float*)d_in[31];
    const float* W2 = (const float*)d_in[32];  const float* b2 = (const float*)d_in[33];
    float* out = (float*)d_out;

    char* base = (char*)d_ws;
    size_t off = 0;
    auto alloc = [&](size_t bytes) {
        char* p = base + off;
        off += (bytes + 255) & ~(size_t)255;
        return p;
    };
    const size_t SD = (size_t)S_ * D_;
    float* e_   = (float*)alloc(6 * D_ * 4);
    float* Q_   = (float*)alloc(SD * 4);
    float* K_   = (float*)alloc(SD * 4);
    float* CK_  = (float*)alloc((size_t)L_ * D_ * 4);
    float* CV_  = (float*)alloc((size_t)L_ * D_ * 4);
    float* qc_  = (float*)alloc((size_t)H_ * 64 * 128 * 4);
    float* kc_  = (float*)alloc((size_t)H_ * 64 * 128 * 4);
    float* vc_  = (float*)alloc((size_t)H_ * 64 * 128 * 4);
    float* oc_  = (float*)alloc((size_t)H_ * 64 * 128 * 4);
    int*   idx_ = (int*)alloc((size_t)H_ * 64 * TOPK * 4);
    short* Nb   = (short*)alloc(SD * 2);
    short* Nlo  = (short*)alloc(SD * 2);   // FFC alias start
    short* Vb   = (short*)alloc(SD * 2);
    short* Gb   = (short*)alloc(SD * 2);
    short* attn_b = (short*)alloc(SD * 2);
    short* enc_b  = (short*)alloc((size_t)L_ * D_ * 2);
    const size_t WDD = (size_t)D_ * D_;
    short* Wqh = (short*)alloc(WDD * 2); short* Wql = (short*)alloc(WDD * 2);
    short* Wkh = (short*)alloc(WDD * 2); short* Wkl = (short*)alloc(WDD * 2);
    short* Wvt = (short*)alloc(WDD * 2); short* Wgt = (short*)alloc(WDD * 2);
    short* Wot = (short*)alloc(WDD * 2);
    short* cWqt = (short*)alloc(WDD * 2); short* cWkt = (short*)alloc(WDD * 2);
    short* cWvt = (short*)alloc(WDD * 2); short* cWot = (short*)alloc(WDD * 2);
    short* W1t = (short*)alloc((size_t)D_ * FF_ * 2);
    short* W2t = (short*)alloc((size_t)D_ * FF_ * 2);
    short* FFC = Nlo;   // alias: Nlo/Vb/Gb dead by FFN time

    const dim3 b256(256);
    const int nSD = S_ * D_;
    const dim3 gSD((nSD + 255) / 256);
    const dim3 gDD(D_ / 64, D_ / 64);

    add_kernel<<<dim3((6 * D_ + 255) / 256), b256, 0, stream>>>(sst, temb, e_, 6 * D_);
    ln_bf16<1, 1><<<dim3(S_), b256, 0, stream>>>(h_in, Nb, Nlo, e_ + D_, e_);

    transpose_w<1><<<gDD, b256, 0, stream>>>(Wq, Wqh, Wql, D_, D_);
    transpose_w<1><<<gDD, b256, 0, stream>>>(Wk, Wkh, Wkl, D_, D_);
    transpose_w<0><<<gDD, b256, 0, stream>>>(Wv, Wvt, nullptr, D_, D_);
    transpose_w<0><<<gDD, b256, 0, stream>>>(Wg, Wgt, nullptr, D_, D_);
    transpose_w<0><<<gDD, b256, 0, stream>>>(Wo, Wot, nullptr, D_, D_);
    transpose_w<0><<<gDD, b256, 0, stream>>>(cWq, cWqt, nullptr, D_, D_);
    transpose_w<0><<<gDD, b256, 0, stream>>>(cWk, cWkt, nullptr, D_, D_);
    transpose_w<0><<<gDD, b256, 0, stream>>>(cWv, cWvt, nullptr, D_, D_);
    transpose_w<0><<<gDD, b256, 0, stream>>>(cWo, cWot, nullptr, D_, D_);
    transpose_w<0><<<dim3(FF_ / 64, D_ / 64), b256, 0, stream>>>(W1, W1t, nullptr, D_, FF_);
    transpose_w<0><<<dim3(D_ / 64, FF_ / 64), b256, 0, stream>>>(W2, W2t, nullptr, FF_, D_);
    cvt_bf16_kernel<<<dim3((L_ * D_ / 4 + 255) / 256), b256, 0, stream>>>(enc, enc_b, L_ * D_ / 4);

    const dim3 gP(D_ / 128, S_ / 128);
    gemm_bf16<0><<<gP, b256, 0, stream>>>(Nb,  Wqh, bq, Q_, nullptr, S_, D_, D_);
    gemm_bf16<1><<<gP, b256, 0, stream>>>(Nb,  Wql, nullptr, Q_, nullptr, S_, D_, D_);
    gemm_bf16<1><<<gP, b256, 0, stream>>>(Nlo, Wqh, nullptr, Q_, nullptr, S_, D_, D_);
    gemm_bf16<0><<<gP, b256, 0, stream>>>(Nb,  Wkh, bk, K_, nullptr, S_, D_, D_);
    gemm_bf16<1><<<gP, b256, 0, stream>>>(Nb,  Wkl, nullptr, K_, nullptr, S_, D_, D_);
    gemm_bf16<1><<<gP, b256, 0, stream>>>(Nlo, Wkh, nullptr, K_, nullptr, S_, D_, D_);
    gemm_bf16<3><<<gP, b256, 0, stream>>>(Nb,  Wvt, bv, nullptr, Vb, S_, D_, D_);
    gemm_bf16<3><<<gP, b256, 0, stream>>>(Nb,  Wgt, bg, nullptr, Gb, S_, D_, D_);

    rms_kernel<<<dim3(S_), b256, 0, stream>>>(Q_, nq_w);
    rms_kernel<<<dim3(S_), b256, 0, stream>>>(K_, nk_w);
    {
        const dim3 g((S_ * (D_ / 2) + 255) / 256);
        rope_kernel<<<g, b256, 0, stream>>>(Q_, cosT, sinT);
        rope_kernel<<<g, b256, 0, stream>>>(K_, cosT, sinT);
    }

    blockmean_f32<<<dim3(H_ * 64), dim3(128), 0, stream>>>(Q_, qc_);
    blockmean_f32<<<dim3(H_ * 64), dim3(128), 0, stream>>>(K_, kc_);
    blockmean_bf16<<<dim3(H_ * 64), dim3(128), 0, stream>>>(Vb, vc_);
    coarse_kernel<<<dim3(H_ * 64), dim3(64), 0, stream>>>(qc_, kc_, vc_, oc_, idx_);

    attn_mfma<0><<<dim3(H_ * 64), b256, 0, stream>>>(
        Q_, K_, Vb, nullptr, Gb, oc_, idx_, attn_b);

    gemm_bf16<0><<<gP, b256, 0, stream>>>(attn_b, Wot, bo, Q_, nullptr, S_, D_, D_);
    residgate_kernel<<<gSD, b256, 0, stream>>>(h_in, Q_, e_ + 2 * D_, K_);

    ln_bf16<0, 0><<<dim3(S_), b256, 0, stream>>>(K_, Nb, nullptr, ln1_w, ln1_b);
    gemm_bf16<0><<<gP, b256, 0, stream>>>(Nb, cWqt, cbq, Q_, nullptr, S_, D_, D_);
    rms_kernel<<<dim3(S_), b256, 0, stream>>>(Q_, cnq_w);

    const dim3 gL(D_ / 128, L_ / 128);
    gemm_bf16<0><<<gL, b256, 0, stream>>>(enc_b, cWkt, cbk, CK_, nullptr, L_, D_, D_);
    rms_kernel<<<dim3(L_), b256, 0, stream>>>(CK_, cnk_w);
    gemm_bf16<0><<<gL, b256, 0, stream>>>(enc_b, cWvt, cbv, CV_, nullptr, L_, D_, D_);

    attn_mfma<1><<<dim3(H_ * 64), b256, 0, stream>>>(
        Q_, CK_, nullptr, CV_, nullptr, nullptr, nullptr, attn_b);
    gemm_bf16<0><<<gP, b256, 0, stream>>>(attn_b, cWot, cbo, Q_, nullptr, S_, D_, D_);
    add_kernel<<<gSD, b256, 0, stream>>>(K_, Q_, K_, nSD);

    ln_bf16<1, 0><<<dim3(S_), b256, 0, stream>>>(K_, Nb, nullptr, e_ + 4 * D_, e_ + 3 * D_);
    for (int c = 0; c < S_ / MCHUNK; c++) {
        gemm_bf16<2><<<dim3(FF_ / 128, MCHUNK / 128), b256, 0, stream>>>(
            Nb + (size_t)c * MCHUNK * D_, W1t, b1, nullptr, FFC, MCHUNK, FF_, D_);
        gemm_bf16<0><<<dim3(D_ / 128, MCHUNK / 128), b256, 0, stream>>>(
            FFC, W2t, b2, Q_ + (size_t)c * MCHUNK * D_, nullptr, MCHUNK, D_, FF_);
    }

    residgate_kernel<<<gSD, b256, 0, stream>>>(K_, Q_, e_ + 5 * D_, out);
}

// Round 6
// 1450.526 us; speedup vs baseline: 14.8134x; 1.0253x over previous
//
#include <hip/hip_runtime.h>
#include <math.h>

// ---------------------------------------------------------------------------
// Round 6: big GEMMs moved to a 256x128x64 8-wave kernel (template-derived:
// stage-early + dbuf + 1 barrier/K-tile + reg-resident frags + setprio).
// FFN unchunked (FFC aliases dead buffers). 128^2 kernel kept for enc GEMMs.
// ---------------------------------------------------------------------------

namespace {
constexpr int S_   = 4096;
constexpr int D_   = 1536;
constexpr int H_   = 12;
constexpr int L_   = 512;
constexpr int TOPK = 8;
constexpr int FF_  = 8960;
constexpr float EPS_   = 1e-6f;
constexpr float SCALE_ = 0.08838834764831845f;   // 128^-0.5
}

typedef __attribute__((ext_vector_type(8))) short short8;
typedef __attribute__((ext_vector_type(4))) float f32x4;

#define AS_GLOBAL __attribute__((address_space(1)))
#define AS_LDS    __attribute__((address_space(3)))

__device__ __forceinline__ short f2bf(float x) {
    uint32_t u = __float_as_uint(x);
    uint32_t r = (u + 0x7FFFu + ((u >> 16) & 1u)) >> 16;
    return (short)r;
}
__device__ __forceinline__ float bf2f(short s) {
    return __uint_as_float(((uint32_t)(uint16_t)s) << 16);
}
__device__ __forceinline__ float gelu_tanh(float x) {
    const float t = tanhf(0.7978845608028654f * (x + 0.044715f * x * x * x));
    return 0.5f * x * (1.f + t);
}

// ---------------------------- reductions -----------------------------------
__device__ __forceinline__ float block_sum_256(float v, float* red) {
#pragma unroll
    for (int off = 32; off > 0; off >>= 1) v += __shfl_down(v, off, 64);
    const int lane = threadIdx.x & 63, w = threadIdx.x >> 6;
    if (lane == 0) red[w] = v;
    __syncthreads();
    v = red[0] + red[1] + red[2] + red[3];
    __syncthreads();
    return v;
}

// ==================== 256x128x64 8-wave MFMA GEMM ==========================
// C(M,N) = A(M,K) @ Bt(N,K)^T. 512 threads, waves: wm=wid>>1 (4 M-quarters),
// wn=wid&1 (2 N-halves); per-wave 64x64 out, acc[4][4] f32x4.
// LDS: A[2][256x64] (32KB each) + B[2][128x64] (16KB) = 96KB, double-buffered.
// Row = 128B = 8x16B units; unit swizzle u_phys = u_log ^ (row&7)  -> 2-way
// (free) on frag ds_read_b128. Staged via global_load_lds with pre-swizzled
// per-lane global source (linear LDS dest). One __syncthreads per K-tile
// (implicit vmcnt(0)+lgkmcnt(0) drain covers prev-issued next-tile stages).
// Requires: M%256==0, N%128==0, K%64==0, nk>=1.
// EPI: 0 C=acc+bias ; 1 C+=acc ; 2 Cb=bf16(gelu(acc+bias)) ; 3 Cb=bf16(acc+bias)
template <int EPI>
__global__ __launch_bounds__(512) void gemm256(
    const short* __restrict__ A, const short* __restrict__ Bt,
    const float* __restrict__ bias, float* __restrict__ C,
    short* __restrict__ Cb, int M, int N, int K)
{
    __shared__ __align__(16) short As[2][256 * 64];
    __shared__ __align__(16) short Bs[2][128 * 64];
    const int tid = threadIdx.x;
    const int wid = tid >> 6, lane = tid & 63;
    const int wm = wid >> 1, wn = wid & 1;
    const int g16 = lane >> 4, l15 = lane & 15;

    // bijective XCD swizzle
    const int nwg = gridDim.x * gridDim.y;
    const int bid = blockIdx.y * gridDim.x + blockIdx.x;
    const int qq = nwg >> 3, r8 = nwg & 7;
    const int xcd = bid & 7, lid = bid >> 3;
    const int swz = ((xcd < r8) ? xcd * (qq + 1) : r8 * (qq + 1) + (xcd - r8) * qq) + lid;
    const int m0 = (swz / gridDim.x) * 256, n0 = (swz % gridDim.x) * 128;

    f32x4 acc[4][4];
#pragma unroll
    for (int i = 0; i < 4; i++)
#pragma unroll
        for (int j = 0; j < 4; j++) acc[i][j] = (f32x4){0.f, 0.f, 0.f, 0.f};

    // staging unit -> (row, swizzled global unit)
    // A: units 0..2047 (4/thread) ; B: units 0..1023 (2/thread)
    int arow[4], aul[4];
#pragma unroll
    for (int i = 0; i < 4; i++) {
        const int c = tid + 512 * i;
        arow[i] = c >> 3;
        aul[i]  = (c & 7) ^ (arow[i] & 7);
    }
    int brow[2], bul[2];
#pragma unroll
    for (int i = 0; i < 2; i++) {
        const int c = tid + 512 * i;
        brow[i] = c >> 3;
        bul[i]  = (c & 7) ^ (brow[i] & 7);
    }

    auto STAGE = [&](int buf, int kt) {
#pragma unroll
        for (int i = 0; i < 4; i++)
            __builtin_amdgcn_global_load_lds(
                (const AS_GLOBAL short*)(A + (size_t)(m0 + arow[i]) * K + kt + aul[i] * 8),
                (AS_LDS short*)(As[buf] + (tid + 512 * i) * 8), 16, 0, 0);
#pragma unroll
        for (int i = 0; i < 2; i++)
            __builtin_amdgcn_global_load_lds(
                (const AS_GLOBAL short*)(Bt + (size_t)(n0 + brow[i]) * K + kt + bul[i] * 8),
                (AS_LDS short*)(Bs[buf] + (tid + 512 * i) * 8), 16, 0, 0);
    };

    const int nk = K >> 6;
    STAGE(0, 0);
    __syncthreads();

    for (int t = 0; t < nk; ++t) {
        const int cur = t & 1;
        if (t + 1 < nk) STAGE(cur ^ 1, (t + 1) << 6);

        short8 a[4][2], b[4][2];
#pragma unroll
        for (int mi = 0; mi < 4; mi++) {
            const int row = wm * 64 + mi * 16 + l15;
#pragma unroll
            for (int kk = 0; kk < 2; kk++) {
                const int u = (kk * 4 + g16) ^ (row & 7);
                a[mi][kk] = *(const short8*)(As[cur] + row * 64 + u * 8);
            }
        }
#pragma unroll
        for (int ni = 0; ni < 4; ni++) {
            const int row = wn * 64 + ni * 16 + l15;
#pragma unroll
            for (int kk = 0; kk < 2; kk++) {
                const int u = (kk * 4 + g16) ^ (row & 7);
                b[ni][kk] = *(const short8*)(Bs[cur] + row * 64 + u * 8);
            }
        }

        __builtin_amdgcn_s_setprio(1);
#pragma unroll
        for (int mi = 0; mi < 4; mi++)
#pragma unroll
            for (int ni = 0; ni < 4; ni++)
#pragma unroll
                for (int kk = 0; kk < 2; kk++)
                    acc[mi][ni] = __builtin_amdgcn_mfma_f32_16x16x32_bf16(
                        a[mi][kk], b[ni][kk], acc[mi][ni], 0, 0, 0);
        __builtin_amdgcn_s_setprio(0);

        __syncthreads();    // drains vmcnt(0): next tile landed; reads done
    }

#pragma unroll
    for (int mi = 0; mi < 4; mi++) {
#pragma unroll
        for (int ni = 0; ni < 4; ni++) {
            const int col = n0 + wn * 64 + ni * 16 + l15;
            const float bv = (EPI == 1) ? 0.f : bias[col];
#pragma unroll
            for (int rr = 0; rr < 4; rr++) {
                const int row = m0 + wm * 64 + mi * 16 + g16 * 4 + rr;
                const size_t o = (size_t)row * N + col;
                float v = acc[mi][ni][rr];
                if (EPI == 0) C[o] = v + bv;
                else if (EPI == 1) C[o] += v;
                else if (EPI == 2) Cb[o] = f2bf(gelu_tanh(v + bv));
                else Cb[o] = f2bf(v + bv);
            }
        }
    }
}

// ==================== 128x128x32 4-wave GEMM (enc only) =====================
template <int EPI>
__global__ __launch_bounds__(256) void gemm_bf16(
    const short* __restrict__ A, const short* __restrict__ Bt,
    const float* __restrict__ bias, float* __restrict__ C,
    short* __restrict__ Cb, int M, int N, int K)
{
    __shared__ __align__(16) short As[3][128 * 32];
    __shared__ __align__(16) short Bs[3][128 * 32];
    const int tid = threadIdx.x;
    const int wid = tid >> 6, lane = tid & 63;
    const int wm = wid >> 1, wn = wid & 1;
    const int g16 = lane >> 4, l15 = lane & 15;
    const int m0 = blockIdx.y * 128, n0 = blockIdx.x * 128;

    f32x4 acc[4][4];
#pragma unroll
    for (int i = 0; i < 4; i++)
#pragma unroll
        for (int j = 0; j < 4; j++) acc[i][j] = (f32x4){0.f, 0.f, 0.f, 0.f};

    const int c0 = tid, c1 = tid + 256;
    const int ar0 = c0 >> 2, au0 = (c0 & 3) ^ ((c0 >> 3) & 3);
    const int ar1 = c1 >> 2, au1 = (c1 & 3) ^ ((c1 >> 3) & 3);

    auto STAGE = [&](int buf, int kt) {
        __builtin_amdgcn_global_load_lds(
            (const AS_GLOBAL short*)(A + (size_t)(m0 + ar0) * K + kt + au0 * 8),
            (AS_LDS short*)(As[buf] + c0 * 8), 16, 0, 0);
        __builtin_amdgcn_global_load_lds(
            (const AS_GLOBAL short*)(A + (size_t)(m0 + ar1) * K + kt + au1 * 8),
            (AS_LDS short*)(As[buf] + c1 * 8), 16, 0, 0);
        __builtin_amdgcn_global_load_lds(
            (const AS_GLOBAL short*)(Bt + (size_t)(n0 + ar0) * K + kt + au0 * 8),
            (AS_LDS short*)(Bs[buf] + c0 * 8), 16, 0, 0);
        __builtin_amdgcn_global_load_lds(
            (const AS_GLOBAL short*)(Bt + (size_t)(n0 + ar1) * K + kt + au1 * 8),
            (AS_LDS short*)(Bs[buf] + c1 * 8), 16, 0, 0);
    };

    const int nk = K >> 5;
    STAGE(0, 0);
    STAGE(1, 32);
    STAGE(2, 64);

    int cur = 0;
    for (int t = 0; t < nk; ++t) {
        if (t < nk - 2)       asm volatile("s_waitcnt vmcnt(8)" ::: "memory");
        else if (t == nk - 2) asm volatile("s_waitcnt vmcnt(4)" ::: "memory");
        else                  asm volatile("s_waitcnt vmcnt(0)" ::: "memory");
        __builtin_amdgcn_s_barrier();
        __builtin_amdgcn_sched_barrier(0);

        short8 a[4], b[4];
#pragma unroll
        for (int i = 0; i < 4; i++) {
            const int row = wm * 64 + i * 16 + l15;
            a[i] = *(const short8*)(As[cur] + row * 32 + (g16 ^ ((row >> 1) & 3)) * 8);
        }
#pragma unroll
        for (int j = 0; j < 4; j++) {
            const int row = wn * 64 + j * 16 + l15;
            b[j] = *(const short8*)(Bs[cur] + row * 32 + (g16 ^ ((row >> 1) & 3)) * 8);
        }
        asm volatile("s_waitcnt lgkmcnt(0)" ::: "memory");
        __builtin_amdgcn_sched_barrier(0);
        __builtin_amdgcn_s_barrier();
        __builtin_amdgcn_sched_barrier(0);

        if (t + 3 < nk) STAGE(cur, (t + 3) << 5);

#pragma unroll
        for (int i = 0; i < 4; i++)
#pragma unroll
            for (int j = 0; j < 4; j++)
                acc[i][j] = __builtin_amdgcn_mfma_f32_16x16x32_bf16(
                    a[i], b[j], acc[i][j], 0, 0, 0);

        cur = (cur == 2) ? 0 : cur + 1;
    }

#pragma unroll
    for (int i = 0; i < 4; i++) {
#pragma unroll
        for (int j = 0; j < 4; j++) {
            const int col = n0 + wn * 64 + j * 16 + l15;
            const float bv = (EPI == 1) ? 0.f : bias[col];
#pragma unroll
            for (int rr = 0; rr < 4; rr++) {
                const int row = m0 + wm * 64 + i * 16 + g16 * 4 + rr;
                const size_t o = (size_t)row * N + col;
                float v = acc[i][j][rr];
                if (EPI == 0) C[o] = v + bv;
                else if (EPI == 1) C[o] += v;
                else if (EPI == 2) Cb[o] = f2bf(gelu_tanh(v + bv));
                else Cb[o] = f2bf(v + bv);
            }
        }
    }
}

// ---------------------- weight transpose / convert -------------------------
template <int SPLIT>
__global__ __launch_bounds__(256) void transpose_w(
    const float* __restrict__ W, short* __restrict__ Th, short* __restrict__ Tl,
    int Kd, int Nd)
{
    __shared__ float tile[64][65];
    const int k0 = blockIdx.y * 64, n0 = blockIdx.x * 64;
    for (int f = threadIdx.x; f < 1024; f += 256) {
        const int rr = f >> 4, c4 = (f & 15) * 4;
        const float4 v = *(const float4*)(W + (size_t)(k0 + rr) * Nd + n0 + c4);
        tile[rr][c4 + 0] = v.x; tile[rr][c4 + 1] = v.y;
        tile[rr][c4 + 2] = v.z; tile[rr][c4 + 3] = v.w;
    }
    __syncthreads();
    for (int f = threadIdx.x; f < 1024; f += 256) {
        const int nn = f >> 4, k4 = (f & 15) * 4;
        short4 hv, lv;
        float w0 = tile[k4 + 0][nn], w1 = tile[k4 + 1][nn];
        float w2 = tile[k4 + 2][nn], w3 = tile[k4 + 3][nn];
        hv.x = f2bf(w0); hv.y = f2bf(w1); hv.z = f2bf(w2); hv.w = f2bf(w3);
        *(short4*)(Th + (size_t)(n0 + nn) * Kd + k0 + k4) = hv;
        if (SPLIT) {
            lv.x = f2bf(w0 - bf2f(hv.x)); lv.y = f2bf(w1 - bf2f(hv.y));
            lv.z = f2bf(w2 - bf2f(hv.z)); lv.w = f2bf(w3 - bf2f(hv.w));
            *(short4*)(Tl + (size_t)(n0 + nn) * Kd + k0 + k4) = lv;
        }
    }
}

__global__ void cvt_bf16_kernel(const float* __restrict__ x, short* __restrict__ y, int n4)
{
    const int i = blockIdx.x * 256 + threadIdx.x;
    if (i >= n4) return;
    const float4 v = *(const float4*)(x + (size_t)i * 4);
    short4 o; o.x = f2bf(v.x); o.y = f2bf(v.y); o.z = f2bf(v.z); o.w = f2bf(v.w);
    *(short4*)(y + (size_t)i * 4) = o;
}

// --------------------- LayerNorm (bf16 out, optional split) -----------------
template <int ADD1, int SPLIT>
__global__ __launch_bounds__(256) void ln_bf16(
    const float* __restrict__ x, short* __restrict__ hi, short* __restrict__ lo,
    const float* __restrict__ g, const float* __restrict__ b)
{
    __shared__ float red[4];
    const size_t s = blockIdx.x;
    const float* xr = x + s * D_;
    float v[6];
    float sm = 0.f;
#pragma unroll
    for (int i = 0; i < 6; i++) { v[i] = xr[threadIdx.x + 256 * i]; sm += v[i]; }
    sm = block_sum_256(sm, red);
    const float mean = sm * (1.f / D_);
    float vs = 0.f;
#pragma unroll
    for (int i = 0; i < 6; i++) { const float d = v[i] - mean; vs += d * d; }
    vs = block_sum_256(vs, red);
    const float rs = rsqrtf(vs * (1.f / D_) + EPS_);
#pragma unroll
    for (int i = 0; i < 6; i++) {
        const int d = threadIdx.x + 256 * i;
        const float y = (v[i] - mean) * rs * (g[d] + (float)ADD1) + b[d];
        const short h = f2bf(y);
        hi[s * D_ + d] = h;
        if (SPLIT) lo[s * D_ + d] = f2bf(y - bf2f(h));
    }
}

__global__ __launch_bounds__(256) void rms_kernel(float* __restrict__ x,
                                                  const float* __restrict__ w)
{
    __shared__ float red[4];
    const size_t s = blockIdx.x;
    float* xr = x + s * D_;
    float v[6];
    float ss = 0.f;
#pragma unroll
    for (int i = 0; i < 6; i++) { v[i] = xr[threadIdx.x + 256 * i]; ss += v[i] * v[i]; }
    ss = block_sum_256(ss, red);
    const float rs = rsqrtf(ss * (1.f / D_) + EPS_);
#pragma unroll
    for (int i = 0; i < 6; i++) {
        const int d = threadIdx.x + 256 * i;
        xr[d] = v[i] * rs * w[d];
    }
}

// ------------------------------- RoPE --------------------------------------
__global__ void rope_kernel(float* __restrict__ x,
                            const float* __restrict__ cosT,
                            const float* __restrict__ sinT)
{
    const int idx = blockIdx.x * 256 + threadIdx.x;
    if (idx >= S_ * (D_ / 2)) return;
    const int s = idx / (D_ / 2), r = idx % (D_ / 2);
    const int h = r >> 6, i = r & 63;
    const size_t base = (size_t)s * D_ + h * 128 + 2 * i;
    const float x1 = x[base], x2 = x[base + 1];
    const float c = cosT[s * 64 + i], sn = sinT[s * 64 + i];
    x[base]     = x1 * c - x2 * sn;
    x[base + 1] = x2 * c + x1 * sn;
}

// --------------------------- elementwise -----------------------------------
__global__ void add_kernel(const float* __restrict__ a, const float* __restrict__ b,
                           float* __restrict__ o, int n)
{
    const int i = blockIdx.x * 256 + threadIdx.x;
    if (i < n) o[i] = a[i] + b[i];
}

__global__ void residgate_kernel(const float* __restrict__ h, const float* __restrict__ x,
                                 const float* __restrict__ gate, float* __restrict__ o)
{
    const int i = blockIdx.x * 256 + threadIdx.x;
    if (i < S_ * D_) { const int d = i % D_; o[i] = h[i] + x[i] * gate[d]; }
}

// ------------------------- VSA coarse path ---------------------------------
__global__ __launch_bounds__(128) void blockmean_f32(const float* __restrict__ q,
                                                     float* __restrict__ qc)
{
    const int hb = blockIdx.x;
    const int h = hb >> 6, j = hb & 63;
    const int d = threadIdx.x;
    float sum = 0.f;
    for (int t = 0; t < 64; t++)
        sum += q[(size_t)(j * 64 + t) * D_ + h * 128 + d];
    qc[(size_t)hb * 128 + d] = sum * (1.f / 64.f);
}

__global__ __launch_bounds__(128) void blockmean_bf16(const short* __restrict__ q,
                                                      float* __restrict__ qc)
{
    const int hb = blockIdx.x;
    const int h = hb >> 6, j = hb & 63;
    const int d = threadIdx.x;
    float sum = 0.f;
    for (int t = 0; t < 64; t++)
        sum += bf2f(q[(size_t)(j * 64 + t) * D_ + h * 128 + d]);
    qc[(size_t)hb * 128 + d] = sum * (1.f / 64.f);
}

__global__ __launch_bounds__(64) void coarse_kernel(
    const float* __restrict__ qc, const float* __restrict__ kc,
    const float* __restrict__ vc, float* __restrict__ oc, int* __restrict__ idxout)
{
    const int hb = blockIdx.x;
    const int h = hb >> 6, i = hb & 63;
    const int lane = threadIdx.x;
    __shared__ float p[64];

    const float* qv = qc + (size_t)hb * 128;
    const float* kv = kc + (size_t)((h << 6) + lane) * 128;
    float sc = 0.f;
    for (int d = 0; d < 128; d++) sc = fmaf(qv[d], kv[d], sc);
    sc *= SCALE_;

    float mx = sc;
#pragma unroll
    for (int off = 32; off > 0; off >>= 1) mx = fmaxf(mx, __shfl_xor(mx, off, 64));
    const float e = expf(sc - mx);
    float sumv = e;
#pragma unroll
    for (int off = 32; off > 0; off >>= 1) sumv += __shfl_xor(sumv, off, 64);
    const float pv = e / sumv;
    p[lane] = pv;
    __syncthreads();

    float o0 = 0.f, o1 = 0.f;
    for (int j = 0; j < 64; j++) {
        const float pj = p[j];
        const float* vr = vc + (size_t)((h << 6) + j) * 128;
        o0 = fmaf(pj, vr[lane], o0);
        o1 = fmaf(pj, vr[lane + 64], o1);
    }
    oc[(size_t)hb * 128 + lane]      = o0;
    oc[(size_t)hb * 128 + lane + 64] = o1;

    float v = pv;
    for (int t = 0; t < TOPK; t++) {
        float bv = v; int bi = lane;
#pragma unroll
        for (int off = 32; off > 0; off >>= 1) {
            const float ov = __shfl_xor(bv, off, 64);
            const int   oi = __shfl_xor(bi, off, 64);
            if (ov > bv || (ov == bv && oi < bi)) { bv = ov; bi = oi; }
        }
        if (lane == 0) idxout[hb * TOPK + t] = bi;
        if (lane == bi) v = -1.f;
    }
}

// ---------------------- MFMA flash attention -------------------------------
template <int MODE>
__global__ __launch_bounds__(256) void attn_mfma(
    const float* __restrict__ Qf, const float* __restrict__ Kf,
    const short* __restrict__ Vbb, const float* __restrict__ Vff,
    const short* __restrict__ Gb, const float* __restrict__ ocp,
    const int* __restrict__ idxp, short* __restrict__ Ob)
{
    const int hb = blockIdx.x, h = hb >> 6, ib = hb & 63;
    const int tid = threadIdx.x, wid = tid >> 6, lane = tid & 63;
    const int g16 = lane >> 4, l15 = lane & 15;

    __shared__ __align__(16) short Ks[64 * 128];
    __shared__ __align__(16) short Vst[128 * 64];
    __shared__ __align__(16) short Ps[64 * 80];
    __shared__ int sel[8];
    if (tid < 8) sel[tid] = (MODE == 0) ? idxp[hb * 8 + tid] : tid;

    short8 qa[4];
    {
        const float* qrow = Qf + (size_t)(ib * 64 + wid * 16 + l15) * D_ + h * 128;
#pragma unroll
        for (int kk = 0; kk < 4; kk++) {
            const float4 f0 = *(const float4*)(qrow + kk * 32 + g16 * 8);
            const float4 f1 = *(const float4*)(qrow + kk * 32 + g16 * 8 + 4);
            short8 v;
            v[0] = f2bf(f0.x); v[1] = f2bf(f0.y); v[2] = f2bf(f0.z); v[3] = f2bf(f0.w);
            v[4] = f2bf(f1.x); v[5] = f2bf(f1.y); v[6] = f2bf(f1.z); v[7] = f2bf(f1.w);
            qa[kk] = v;
        }
    }

    f32x4 o[8];
#pragma unroll
    for (int n2 = 0; n2 < 8; n2++) o[n2] = (f32x4){0.f, 0.f, 0.f, 0.f};
    float mrow[4] = {-3e38f, -3e38f, -3e38f, -3e38f};
    float lrow[4] = {0.f, 0.f, 0.f, 0.f};
    __syncthreads();

    for (int t = 0; t < 8; t++) {
        const int jb = sel[t];
#pragma unroll
        for (int it = 0; it < 4; it++) {
            const int c = tid + 256 * it;
            const int key = c >> 4, d8 = (c & 15) * 8;
            const float* src = Kf + (size_t)(jb * 64 + key) * D_ + h * 128 + d8;
            const float4 f0 = *(const float4*)src;
            const float4 f1 = *(const float4*)(src + 4);
            short8 v;
            v[0] = f2bf(f0.x); v[1] = f2bf(f0.y); v[2] = f2bf(f0.z); v[3] = f2bf(f0.w);
            v[4] = f2bf(f1.x); v[5] = f2bf(f1.y); v[6] = f2bf(f1.z); v[7] = f2bf(f1.w);
            const int byte = (key * 256 + d8 * 2) ^ ((key & 7) << 4);
            *(short8*)((char*)Ks + byte) = v;
        }
#pragma unroll
        for (int it = 0; it < 4; it++) {
            const int c = tid + 256 * it;
            const int key = c & 63, d8 = (c >> 6) * 8;
            float vv[8];
            if (MODE == 0) {
                const short8 v = *(const short8*)(Vbb + (size_t)(jb * 64 + key) * D_ + h * 128 + d8);
#pragma unroll
                for (int j = 0; j < 8; j++) vv[j] = bf2f(v[j]);
            } else {
                const float* src = Vff + (size_t)(jb * 64 + key) * D_ + h * 128 + d8;
                const float4 f0 = *(const float4*)src;
                const float4 f1 = *(const float4*)(src + 4);
                vv[0] = f0.x; vv[1] = f0.y; vv[2] = f0.z; vv[3] = f0.w;
                vv[4] = f1.x; vv[5] = f1.y; vv[6] = f1.z; vv[7] = f1.w;
            }
#pragma unroll
            for (int j = 0; j < 8; j++) {
                const int dim = d8 + j;
                const int byte = (dim * 128 + key * 2) ^ ((dim & 7) << 4);
                *(short*)((char*)Vst + byte) = f2bf(vv[j]);
            }
        }
        __syncthreads();

        f32x4 s[4];
#pragma unroll
        for (int nt = 0; nt < 4; nt++) {
            f32x4 acc = (f32x4){0.f, 0.f, 0.f, 0.f};
            const int key = nt * 16 + l15;
#pragma unroll
            for (int kk = 0; kk < 4; kk++) {
                const int byte = (key * 256 + (kk * 32 + g16 * 8) * 2) ^ ((key & 7) << 4);
                const short8 b = *(const short8*)((char*)Ks + byte);
                acc = __builtin_amdgcn_mfma_f32_16x16x32_bf16(qa[kk], b, acc, 0, 0, 0);
            }
            s[nt] = acc;
        }
#pragma unroll
        for (int nt = 0; nt < 4; nt++)
#pragma unroll
            for (int rr = 0; rr < 4; rr++) s[nt][rr] *= SCALE_;

        float alpha[4];
#pragma unroll
        for (int rr = 0; rr < 4; rr++) {
            float v = fmaxf(fmaxf(s[0][rr], s[1][rr]), fmaxf(s[2][rr], s[3][rr]));
            v = fmaxf(v, __shfl_xor(v, 1, 64));
            v = fmaxf(v, __shfl_xor(v, 2, 64));
            v = fmaxf(v, __shfl_xor(v, 4, 64));
            v = fmaxf(v, __shfl_xor(v, 8, 64));
            const float mn = fmaxf(mrow[rr], v);
            alpha[rr] = expf(mrow[rr] - mn);
            mrow[rr] = mn;
        }
        float rs[4] = {0.f, 0.f, 0.f, 0.f};
#pragma unroll
        for (int nt = 0; nt < 4; nt++)
#pragma unroll
            for (int rr = 0; rr < 4; rr++) {
                const float p = expf(s[nt][rr] - mrow[rr]);
                s[nt][rr] = p;
                rs[rr] += p;
            }
#pragma unroll
        for (int rr = 0; rr < 4; rr++) {
            float v = rs[rr];
            v += __shfl_xor(v, 1, 64);
            v += __shfl_xor(v, 2, 64);
            v += __shfl_xor(v, 4, 64);
            v += __shfl_xor(v, 8, 64);
            lrow[rr] = lrow[rr] * alpha[rr] + v;
        }
#pragma unroll
        for (int n2 = 0; n2 < 8; n2++)
#pragma unroll
            for (int rr = 0; rr < 4; rr++) o[n2][rr] *= alpha[rr];

#pragma unroll
        for (int nt = 0; nt < 4; nt++)
#pragma unroll
            for (int rr = 0; rr < 4; rr++)
                Ps[(wid * 16 + g16 * 4 + rr) * 80 + nt * 16 + l15] = f2bf(s[nt][rr]);

#pragma unroll
        for (int kk2 = 0; kk2 < 2; kk2++) {
            const short8 pa = *(const short8*)(Ps + (wid * 16 + l15) * 80 + kk2 * 32 + g16 * 8);
#pragma unroll
            for (int n2 = 0; n2 < 8; n2++) {
                const int dim = n2 * 16 + l15;
                const int byte = (dim * 128 + (kk2 * 32 + g16 * 8) * 2) ^ ((dim & 7) << 4);
                const short8 vb = *(const short8*)((char*)Vst + byte);
                o[n2] = __builtin_amdgcn_mfma_f32_16x16x32_bf16(pa, vb, o[n2], 0, 0, 0);
            }
        }
        __syncthreads();
    }

#pragma unroll
    for (int n2 = 0; n2 < 8; n2++) {
        const int col = n2 * 16 + l15;
        const float ocv = (MODE == 0) ? ocp[(size_t)hb * 128 + col] : 0.f;
#pragma unroll
        for (int rr = 0; rr < 4; rr++) {
            const int row = ib * 64 + wid * 16 + g16 * 4 + rr;
            float val = o[n2][rr] / lrow[rr];
            if (MODE == 0)
                val += ocv * bf2f(Gb[(size_t)row * D_ + h * 128 + col]);
            Ob[(size_t)row * D_ + h * 128 + col] = f2bf(val);
        }
    }
}

// ---------------------------------------------------------------------------
extern "C" void kernel_launch(void* const* d_in, const int* in_sizes, int n_in,
                              void* d_out, int out_size, void* d_ws, size_t ws_size,
                              hipStream_t stream)
{
    const float* h_in = (const float*)d_in[0];
    const float* enc  = (const float*)d_in[1];
    const float* temb = (const float*)d_in[2];
    const float* cosT = (const float*)d_in[3];
    const float* sinT = (const float*)d_in[4];
    const float* sst  = (const float*)d_in[5];
    const float* Wq = (const float*)d_in[6];   const float* bq = (const float*)d_in[7];
    const float* Wk = (const float*)d_in[8];   const float* bk = (const float*)d_in[9];
    const float* Wv = (const float*)d_in[10];  const float* bv = (const float*)d_in[11];
    const float* Wg = (const float*)d_in[12];  const float* bg = (const float*)d_in[13];
    const float* Wo = (const float*)d_in[14];  const float* bo = (const float*)d_in[15];
    const float* nq_w  = (const float*)d_in[16];
    const float* nk_w  = (const float*)d_in[17];
    const float* ln1_w = (const float*)d_in[18];
    const float* ln1_b = (const float*)d_in[19];
    const float* cWq = (const float*)d_in[20]; const float* cbq = (const float*)d_in[21];
    const float* cWk = (const float*)d_in[22]; const float* cbk = (const float*)d_in[23];
    const float* cWv = (const float*)d_in[24]; const float* cbv = (const float*)d_in[25];
    const float* cWo = (const float*)d_in[26]; const float* cbo = (const float*)d_in[27];
    const float* cnq_w = (const float*)d_in[28];
    const float* cnk_w = (const float*)d_in[29];
    const float* W1 = (const float*)d_in[30];  const float* b1 = (const float*)d_in[31];
    const float* W2 = (const float*)d_in[32];  const float* b2 = (const float*)d_in[33];
    float* out = (float*)d_out;

    char* base = (char*)d_ws;
    size_t off = 0;
    auto alloc = [&](size_t bytes) {
        char* p = base + off;
        off += (bytes + 255) & ~(size_t)255;
        return p;
    };
    const size_t SD = (size_t)S_ * D_;
    float* e_   = (float*)alloc(6 * D_ * 4);
    float* Q_   = (float*)alloc(SD * 4);
    float* K_   = (float*)alloc(SD * 4);
    float* CK_  = (float*)alloc((size_t)L_ * D_ * 4);
    float* CV_  = (float*)alloc((size_t)L_ * D_ * 4);
    float* qc_  = (float*)alloc((size_t)H_ * 64 * 128 * 4);
    float* kc_  = (float*)alloc((size_t)H_ * 64 * 128 * 4);
    float* vc_  = (float*)alloc((size_t)H_ * 64 * 128 * 4);
    float* oc_  = (float*)alloc((size_t)H_ * 64 * 128 * 4);
    int*   idx_ = (int*)alloc((size_t)H_ * 64 * TOPK * 4);
    short* Nb   = (short*)alloc(SD * 2);
    // ---- FFC alias region starts here: Nlo..Wgt = ~80 MB, all dead by FFN ----
    short* Nlo  = (short*)alloc(SD * 2);
    short* Vb   = (short*)alloc(SD * 2);
    short* Gb   = (short*)alloc(SD * 2);
    short* attn_b = (short*)alloc(SD * 2);
    short* enc_b  = (short*)alloc((size_t)L_ * D_ * 2);
    const size_t WDD = (size_t)D_ * D_;
    short* Wqh = (short*)alloc(WDD * 2); short* Wql = (short*)alloc(WDD * 2);
    short* Wkh = (short*)alloc(WDD * 2); short* Wkl = (short*)alloc(WDD * 2);
    short* Wvt = (short*)alloc(WDD * 2); short* Wgt = (short*)alloc(WDD * 2);
    // ---- end alias region (FFC needs S*FF*2 = 73.4 MB < region) ----
    short* Wot = (short*)alloc(WDD * 2);
    short* cWqt = (short*)alloc(WDD * 2); short* cWkt = (short*)alloc(WDD * 2);
    short* cWvt = (short*)alloc(WDD * 2); short* cWot = (short*)alloc(WDD * 2);
    short* W1t = (short*)alloc((size_t)D_ * FF_ * 2);
    short* W2t = (short*)alloc((size_t)D_ * FF_ * 2);
    short* FFC = Nlo;   // full S x FF bf16 (73.4 MB) over dead buffers

    const dim3 b256(256);
    const int nSD = S_ * D_;
    const dim3 gSD((nSD + 255) / 256);
    const dim3 gDD(D_ / 64, D_ / 64);
    const dim3 b512(512);
    const dim3 gQ(D_ / 128, S_ / 256);       // 256x128 tiles, M=S

    add_kernel<<<dim3((6 * D_ + 255) / 256), b256, 0, stream>>>(sst, temb, e_, 6 * D_);
    ln_bf16<1, 1><<<dim3(S_), b256, 0, stream>>>(h_in, Nb, Nlo, e_ + D_, e_);

    transpose_w<1><<<gDD, b256, 0, stream>>>(Wq, Wqh, Wql, D_, D_);
    transpose_w<1><<<gDD, b256, 0, stream>>>(Wk, Wkh, Wkl, D_, D_);
    transpose_w<0><<<gDD, b256, 0, stream>>>(Wv, Wvt, nullptr, D_, D_);
    transpose_w<0><<<gDD, b256, 0, stream>>>(Wg, Wgt, nullptr, D_, D_);
    transpose_w<0><<<gDD, b256, 0, stream>>>(Wo, Wot, nullptr, D_, D_);
    transpose_w<0><<<gDD, b256, 0, stream>>>(cWq, cWqt, nullptr, D_, D_);
    transpose_w<0><<<gDD, b256, 0, stream>>>(cWk, cWkt, nullptr, D_, D_);
    transpose_w<0><<<gDD, b256, 0, stream>>>(cWv, cWvt, nullptr, D_, D_);
    transpose_w<0><<<gDD, b256, 0, stream>>>(cWo, cWot, nullptr, D_, D_);
    transpose_w<0><<<dim3(FF_ / 64, D_ / 64), b256, 0, stream>>>(W1, W1t, nullptr, D_, FF_);
    transpose_w<0><<<dim3(D_ / 64, FF_ / 64), b256, 0, stream>>>(W2, W2t, nullptr, FF_, D_);
    cvt_bf16_kernel<<<dim3((L_ * D_ / 4 + 255) / 256), b256, 0, stream>>>(enc, enc_b, L_ * D_ / 4);

    // q,k (split-bf16, 3 passes), v,g
    gemm256<0><<<gQ, b512, 0, stream>>>(Nb,  Wqh, bq, Q_, nullptr, S_, D_, D_);
    gemm256<1><<<gQ, b512, 0, stream>>>(Nb,  Wql, nullptr, Q_, nullptr, S_, D_, D_);
    gemm256<1><<<gQ, b512, 0, stream>>>(Nlo, Wqh, nullptr, Q_, nullptr, S_, D_, D_);
    gemm256<0><<<gQ, b512, 0, stream>>>(Nb,  Wkh, bk, K_, nullptr, S_, D_, D_);
    gemm256<1><<<gQ, b512, 0, stream>>>(Nb,  Wkl, nullptr, K_, nullptr, S_, D_, D_);
    gemm256<1><<<gQ, b512, 0, stream>>>(Nlo, Wkh, nullptr, K_, nullptr, S_, D_, D_);
    gemm256<3><<<gQ, b512, 0, stream>>>(Nb,  Wvt, bv, nullptr, Vb, S_, D_, D_);
    gemm256<3><<<gQ, b512, 0, stream>>>(Nb,  Wgt, bg, nullptr, Gb, S_, D_, D_);

    rms_kernel<<<dim3(S_), b256, 0, stream>>>(Q_, nq_w);
    rms_kernel<<<dim3(S_), b256, 0, stream>>>(K_, nk_w);
    {
        const dim3 g((S_ * (D_ / 2) + 255) / 256);
        rope_kernel<<<g, b256, 0, stream>>>(Q_, cosT, sinT);
        rope_kernel<<<g, b256, 0, stream>>>(K_, cosT, sinT);
    }

    blockmean_f32<<<dim3(H_ * 64), dim3(128), 0, stream>>>(Q_, qc_);
    blockmean_f32<<<dim3(H_ * 64), dim3(128), 0, stream>>>(K_, kc_);
    blockmean_bf16<<<dim3(H_ * 64), dim3(128), 0, stream>>>(Vb, vc_);
    coarse_kernel<<<dim3(H_ * 64), dim3(64), 0, stream>>>(qc_, kc_, vc_, oc_, idx_);

    attn_mfma<0><<<dim3(H_ * 64), b256, 0, stream>>>(
        Q_, K_, Vb, nullptr, Gb, oc_, idx_, attn_b);

    gemm256<0><<<gQ, b512, 0, stream>>>(attn_b, Wot, bo, Q_, nullptr, S_, D_, D_);
    residgate_kernel<<<gSD, b256, 0, stream>>>(h_in, Q_, e_ + 2 * D_, K_);

    ln_bf16<0, 0><<<dim3(S_), b256, 0, stream>>>(K_, Nb, nullptr, ln1_w, ln1_b);
    gemm256<0><<<gQ, b512, 0, stream>>>(Nb, cWqt, cbq, Q_, nullptr, S_, D_, D_);
    rms_kernel<<<dim3(S_), b256, 0, stream>>>(Q_, cnq_w);

    const dim3 gL(D_ / 128, L_ / 128);
    gemm_bf16<0><<<gL, b256, 0, stream>>>(enc_b, cWkt, cbk, CK_, nullptr, L_, D_, D_);
    rms_kernel<<<dim3(L_), b256, 0, stream>>>(CK_, cnk_w);
    gemm_bf16<0><<<gL, b256, 0, stream>>>(enc_b, cWvt, cbv, CV_, nullptr, L_, D_, D_);

    attn_mfma<1><<<dim3(H_ * 64), b256, 0, stream>>>(
        Q_, CK_, nullptr, CV_, nullptr, nullptr, nullptr, attn_b);
    gemm256<0><<<gQ, b512, 0, stream>>>(attn_b, cWot, cbo, Q_, nullptr, S_, D_, D_);
    add_kernel<<<gSD, b256, 0, stream>>>(K_, Q_, K_, nSD);

    // norm3 -> Nb ; FFN unchunked: W1 (S x FF) then W2 (S x D)
    ln_bf16<1, 0><<<dim3(S_), b256, 0, stream>>>(K_, Nb, nullptr, e_ + 4 * D_, e_ + 3 * D_);
    gemm256<2><<<dim3(FF_ / 128, S_ / 256), b512, 0, stream>>>(
        Nb, W1t, b1, nullptr, FFC, S_, FF_, D_);
    gemm256<0><<<gQ, b512, 0, stream>>>(FFC, W2t, b2, Q_, nullptr, S_, D_, FF_);

    residgate_kernel<<<gSD, b256, 0, stream>>>(K_, Q_, e_ + 5 * D_, out);
}